// Round 5
// baseline (639.235 us; speedup 1.0000x reference)
//
#include <hip/hip_runtime.h>
#include <hip/hip_bf16.h>

#define EC 1048576   // conformer edges
#define NN 65536     // conformer nodes
#define NT 8192      // topo nodes
#define MM 256
#define HH 128
#define FF 64
#define GG 50
#define EG 32768     // graph edges

#define TBL 2048            // Wf table entries per layer (512KB/layer -> L2-resident)
#define TBL_SHIFT 11
#define TRANGE 14.0f

#define CAP 32              // padded-CSR slots per node (Poisson(16); overflow list handles tail)
#define OVF_CAP 8192        // overflow list capacity (writes/reads hard-bounded)
#define NEB (NN * 64 / 256)     // edge-agg blocks in merged dispatch

// sentinel pay: table index 2047 (never produced by real edges: i0<=2046), fr=0, row=0
// table2[2047] is forced to {0,0} -> contribution exactly 0 without any masking
#define SENT 0xFFE00000

constexpr float STEP = 10.0f / 49.0f;
constexpr float GC = -0.5f / (STEP * STEP);

typedef __attribute__((ext_vector_type(8))) short bf16x8;
typedef __attribute__((ext_vector_type(4))) float f32x4;

__device__ __forceinline__ ushort f2b(float v) {
    __hip_bfloat16 h = __float2bfloat16(v);
    return *(ushort*)&h;
}
__device__ __forceinline__ float b2f(ushort u) {
    return __uint_as_float(((unsigned)u) << 16);
}

// ---------------- weight prep helper ----------------
__device__ __forceinline__ void prep_one(
    const float* __restrict__ W, ushort* __restrict__ Wf, int K, int N, int idx)
{
    int sz = K * N;
    int l = idx / sz;
    int t = idx - l * sz;
    int j = t & 7;
    int lane = (t >> 3) & 63;
    int rest = t >> 9;
    int KTl = K >> 5;
    int kt = rest % KTl;
    int nt = rest / KTl;
    int k = kt * 32 + (lane >> 4) * 8 + j;
    int n = nt * 16 + (lane & 15);
    Wf[idx] = f2b(W[(size_t)l * sz + (size_t)k * N + n]);
}

// ---------------- mega setup: scatter + ghist + embed + Wf-table + weight prep ----------------
// Block ranges (scatter first: latency-bound waves saturate while the rest streams in):
//   [0, B0)            distance + padded-CSR scatter (nt stores)
//   [B0, B1)           graph-edge histogram
//   [B1, B2)           embedding broadcast (8 feats/thread)
//   [B2, B3)           Wf table build (4 entries/block, one per wave)
//   [B3, B4)           weight prep (5 matrices)
// pay_pad sentinel-filled + cntA/ovf_cnt zeroed BEFORE this kernel.
#define SETUP_B0 (EC / 256)
#define SETUP_B1 (SETUP_B0 + EG / 256)
#define SETUP_B2 (SETUP_B1 + NN * HH / 8 / 256)
#define SETUP_B3 (SETUP_B2 + 4 * TBL / 4)
#define SETUP_B4 (SETUP_B3 + 1024)
__global__ __launch_bounds__(256) void setup_kernel(
    const int* __restrict__ eic, const int* __restrict__ cnb,
    const int* __restrict__ eig, const float* __restrict__ pos,
    const float* __restrict__ emb, const int* __restrict__ xtopo,
    int* __restrict__ degC, ushort* __restrict__ xb,
    int* __restrict__ cntA, int* __restrict__ pay_pad,
    int* __restrict__ ovf_cnt, int2* __restrict__ ovf,
    const float* __restrict__ mw1, const float* __restrict__ mb1,
    const float* __restrict__ mw2, const float* __restrict__ mb2,
    float* __restrict__ table_all,
    const float* __restrict__ cf_lin1_w, const float* __restrict__ cf_lin2_w,
    const float* __restrict__ lin_w, const float* __restrict__ gin_w1,
    const float* __restrict__ gin_w2,
    ushort* __restrict__ w1f, ushort* __restrict__ w2f, ushort* __restrict__ wlf,
    ushort* __restrict__ gw1f, ushort* __restrict__ gw2f)
{
    int b = blockIdx.x, tid = threadIdx.x;
    if (b < SETUP_B0) {
        // distance + direct padded-CSR scatter; nt stores avoid cross-XCD line thrash
        int e = b * 256 + tid;
        int r = eic[e], c = eic[EC + e];
        float dx = pos[r*3+0] - pos[c*3+0];
        float dy = pos[r*3+1] - pos[c*3+1];
        float dz = pos[r*3+2] - pos[c*3+2];
        float w = sqrtf(dx*dx + dy*dy + dz*dz + 1e-12f);
        float u = fminf(w * ((TBL - 1) / TRANGE), 2046.96875f);
        int pay = (((int)(u * 32.0f)) << 16) | (r & 0xFFFF);   // 11.5 fixed point | row
        int slot = atomicAdd(&cntA[c], 1);
        if (slot < CAP) {
            __builtin_nontemporal_store(pay, &pay_pad[c * CAP + slot]);
        } else {
            int o = atomicAdd(ovf_cnt, 1);
            if (o < OVF_CAP) ovf[o] = make_int2(c, pay);   // hard bound
        }
    } else if (b < SETUP_B1) {
        atomicAdd(&degC[eig[EG + (b - SETUP_B0) * 256 + tid]], 1);
    } else if (b < SETUP_B2) {
        // vectorized embedding broadcast: 8 features per thread
        int idx = (b - SETUP_B1) * 256 + tid;   // 0 .. NN*HH/8
        int n = idx >> 4;
        int f8 = (idx & 15) << 3;
        const float* e = emb + (size_t)xtopo[cnb[n]] * HH + f8;
        float4 v0 = *(const float4*)e;
        float4 v1 = *(const float4*)(e + 4);
        ushort u[8] = {f2b(v0.x), f2b(v0.y), f2b(v0.z), f2b(v0.w),
                       f2b(v1.x), f2b(v1.y), f2b(v1.z), f2b(v1.w)};
        *(bf16x8*)(xb + ((size_t)idx << 3)) = *(const bf16x8*)u;
    } else if (b < SETUP_B3) {
        // Wf table: 4 entries per block, one per wave
        int entry = (b - SETUP_B2) * 4 + (tid >> 6);
        int l = entry >> TBL_SHIFT;
        int p = entry & (TBL - 1);
        int lane = tid & 63;
        int wv = tid >> 6;
        const float* w1 = mw1 + (size_t)l * GG * FF;
        const float* b1 = mb1 + (size_t)l * FF;
        const float* w2 = mw2 + (size_t)l * FF * FF;
        const float* b2 = mb2 + (size_t)l * FF;
        float w = p * (TRANGE / (TBL - 1));
        float t = b1[lane];
        for (int g = 0; g < GG; g++) {
            float d = w - g * STEP;
            float ea = __expf(GC * d * d);
            t = fmaf(ea, w1[g * 64 + lane], t);
        }
        __shared__ float ts[4][64];
        ts[wv][lane] = fmaxf(t, 0.f);
        __syncthreads();
        float wf = b2[lane];
        for (int i = 0; i < 64; i++)
            wf = fmaf(ts[wv][i], w2[i * 64 + lane], wf);
        float cw = 0.5f * (__cosf(w * (3.14159265358979323846f / 10.0f)) + 1.0f);
        table_all[((size_t)l * TBL + p) * 64 + lane] = wf * cw;
    } else {
        int pb = b - SETUP_B3;
        if (pb < 128)       prep_one(cf_lin1_w, w1f, HH, FF, pb * 256 + tid);
        else if (pb < 256)  prep_one(cf_lin2_w, w2f, FF, HH, (pb - 128) * 256 + tid);
        else if (pb < 512)  prep_one(lin_w, wlf, HH, HH, (pb - 256) * 256 + tid);
        else if (pb < 768)  prep_one(gin_w1, gw1f, HH, HH, (pb - 512) * 256 + tid);
        else                prep_one(gin_w2, gw2f, HH, HH, (pb - 768) * 256 + tid);
    }
}

// ---------------- single-block exclusive scan for chain C (NT bins) ----------------
__global__ __launch_bounds__(256) void scanC_kernel(
    const int* __restrict__ degC, int* __restrict__ offsC, int* __restrict__ curC)
{
    __shared__ int s[256];
    __shared__ int base;
    int tid = threadIdx.x;
    if (tid == 0) base = 0;
    __syncthreads();
    for (int c = 0; c < NT / 256; c++) {
        int v = degC[c * 256 + tid];
        s[tid] = v;
        __syncthreads();
        for (int off = 1; off < 256; off <<= 1) {
            int t = (tid >= off) ? s[tid - off] : 0;
            __syncthreads();
            s[tid] += t;
            __syncthreads();
        }
        int excl = s[tid] - v + base;
        offsC[c * 256 + tid] = excl;
        curC[c * 256 + tid] = excl;
        __syncthreads();
        if (tid == 255) base += s[255];
        __syncthreads();
    }
    if (tid == 0) offsC[NT] = EG;
}

// ---------------- graph-edge scatter only ----------------
__global__ __launch_bounds__(256) void scatter_graph_kernel(
    const int* __restrict__ eig, const int* __restrict__ eattr,
    int* __restrict__ curC, int2* __restrict__ gpay)
{
    int e = blockIdx.x * 256 + threadIdx.x;
    int p = atomicAdd(&curC[eig[EG + e]], 1);
    gpay[p] = make_int2(eig[e], eattr[e]);
}

// pack fp32 table -> {t0, dt/32} bf16 pair; entry TBL-1 forced to {0,0} (sentinel target)
__global__ __launch_bounds__(256) void pack_table_kernel(
    const float* __restrict__ table_all, ushort2* __restrict__ table2_all)
{
    int idx = blockIdx.x * 256 + threadIdx.x;   // 4*TBL*64
    int f = idx & 63;
    int rest = idx >> 6;
    int i = rest & (TBL - 1);
    int l = rest >> TBL_SHIFT;
    if (i == TBL - 1) {
        table2_all[idx] = make_ushort2(0, 0);
        return;
    }
    const float* T = table_all + ((size_t)l * TBL) * 64;
    float t0 = T[(size_t)i * 64 + f];
    float t1 = T[(size_t)(i + 1) * 64 + f];
    // dt prescaled by 1/32 (exact pow2 shift in bf16): wf = fmaf(dts, (float)frac5, t0)
    table2_all[idx] = make_ushort2(f2b(t0), f2b((t1 - t0) * 0.03125f));
}

// ---------------- plain bf16 MFMA GEMM (initial h1b only), N=64 K=128 ----------------
__global__ __launch_bounds__(256) void gemm_bf16_kernel(
    const ushort* __restrict__ A, const ushort* __restrict__ Bf,
    ushort* __restrict__ Cb)
{
    int tid = threadIdx.x;
    int wave = tid >> 6, lane = tid & 63;
    int m0 = (blockIdx.x * 4 + wave) * 16;
    int arow = m0 + (lane & 15);
    int ak = (lane >> 4) * 8;
    bf16x8 a[4];
    const ushort* Ap = A + (size_t)arow * 128 + ak;
    #pragma unroll
    for (int kt = 0; kt < 4; kt++)
        a[kt] = *(const bf16x8*)(Ap + kt * 32);
    f32x4 acc[4];
    #pragma unroll
    for (int i = 0; i < 4; i++) acc[i] = (f32x4){0.f, 0.f, 0.f, 0.f};
    const ushort* Bp = Bf + (size_t)lane * 8;
    #pragma unroll
    for (int nt = 0; nt < 4; nt++)
        #pragma unroll
        for (int kt = 0; kt < 4; kt++) {
            bf16x8 b = *(const bf16x8*)(Bp + ((size_t)(nt * 4 + kt)) * 512);
            acc[nt] = __builtin_amdgcn_mfma_f32_16x16x32_bf16(a[kt], b, acc[nt], 0, 0, 0);
        }
    int col0 = lane & 15;
    int rbase = m0 + (lane >> 4) * 4;
    #pragma unroll
    for (int nt = 0; nt < 4; nt++) {
        int col = nt * 16 + col0;
        #pragma unroll
        for (int r = 0; r < 4; r++)
            Cb[(size_t)(rbase + r) * 64 + col] = f2b(acc[nt][r]);
    }
}

// 8-wide edge batch, NO masking (sentinel pays -> exact 0 contribution).
// pp is wave-uniform; pays forced to SGPR via readfirstlane so all the
// unpack/address math runs on the SALU pipe; gathers are saddr+voffset32.
#define EDGE8(BASE) { \
    int pq[8]; \
    { int4 q0 = *(const int4*)(pp + BASE); \
      int4 q1 = *(const int4*)(pp + BASE + 4); \
      pq[0]=__builtin_amdgcn_readfirstlane(q0.x); \
      pq[1]=__builtin_amdgcn_readfirstlane(q0.y); \
      pq[2]=__builtin_amdgcn_readfirstlane(q0.z); \
      pq[3]=__builtin_amdgcn_readfirstlane(q0.w); \
      pq[4]=__builtin_amdgcn_readfirstlane(q1.x); \
      pq[5]=__builtin_amdgcn_readfirstlane(q1.y); \
      pq[6]=__builtin_amdgcn_readfirstlane(q1.z); \
      pq[7]=__builtin_amdgcn_readfirstlane(q1.w); } \
    float h[8]; \
    _Pragma("unroll") \
    for (int q = 0; q < 8; q++) \
        h[q] = b2f(*(const ushort*)(h1c + ((((unsigned)(pq[q] & 0xFFFF)) << 7) + lane2))); \
    unsigned tt[8]; \
    _Pragma("unroll") \
    for (int q = 0; q < 8; q++) \
        tt[q] = *(const unsigned*)(tbc + (((((unsigned)pq[q]) >> 21) << 8) + lane4)); \
    _Pragma("unroll") \
    for (int q = 0; q < 8; q++) { \
        float fr = (float)((unsigned)((pq[q] >> 16) & 31)); \
        float t0 = __uint_as_float(tt[q] << 16); \
        float dts = __uint_as_float(tt[q] & 0xFFFF0000u); \
        float wf = fmaf(dts, fr, t0); \
        if (q & 1) acc1 = fmaf(h[q], wf, acc1); else acc0 = fmaf(h[q], wf, acc0); \
    } }

// ---------------- merged: padded-CSR edge aggregation + closed-form xagg max ----------------
__global__ __launch_bounds__(256) void edge_xagg_kernel(
    const int* __restrict__ cntA, const int* __restrict__ pay_pad,
    const int* __restrict__ ovf_cnt, const int2* __restrict__ ovf,
    const ushort2* __restrict__ table2, const ushort* __restrict__ h1b,
    ushort* __restrict__ aggb,
    const ushort* __restrict__ xb, ushort* __restrict__ xaggb)
{
    int tid = threadIdx.x;
    if (blockIdx.x < NEB) {
        int lane = tid & 63;
        int node = __builtin_amdgcn_readfirstlane((blockIdx.x * 256 + tid) >> 6);
        unsigned lane2 = (unsigned)lane * 2;
        unsigned lane4 = (unsigned)lane * 4;
        const char* h1c = (const char*)h1b;
        const char* tbc = (const char*)table2;
        int deg = cntA[node];
        int n1 = min(deg, CAP);
        const int* pp = pay_pad + (size_t)node * CAP;
        float acc0 = 0.f, acc1 = 0.f;
        EDGE8(0);
        if (n1 > 8) {
            EDGE8(8);
            if (n1 > 16) {
                EDGE8(16);
                if (n1 > 24) EDGE8(24);
            }
        }
        float acc = acc0 + acc1;
        if (deg > CAP) {   // rare overflow path (Poisson(16) tail): scan tiny list
            int no = min(*ovf_cnt, OVF_CAP);   // hard bound
            for (int j = 0; j < no; j++) {
                int2 o = ovf[j];
                if (o.x == node) {
                    unsigned uf = (unsigned)o.y >> 16;
                    int i0 = uf >> 5;
                    float fr = (float)(uf & 31);
                    ushort2 ttv = table2[(size_t)i0 * 64 + lane];
                    acc = fmaf(b2f(h1b[(size_t)(o.y & 0xFFFF) * 64 + lane]),
                               fmaf(b2f(ttv.y), fr, b2f(ttv.x)), acc);
                }
            }
        }
        aggb[(size_t)node * 64 + lane] = f2b(acc);
    } else {
        int idx = (blockIdx.x - NEB) * 256 + tid;   // NT*HH
        int tn = idx >> 7, f = idx & 127;
        int m = tn >> 5, a = tn & 31;
        const ushort* base = xb + ((size_t)((m << 8) + a)) * HH + f;
        float mx = -3.4e38f;
        #pragma unroll
        for (int k = 0; k < 8; k++)
            mx = fmaxf(mx, b2f(base[(size_t)(k << 5) * HH]));
        xaggb[idx] = f2b(mx);
    }
}

#define TSTR 136

// ---------------- GIN GEMM1 with fused magg/hg0 tile build + stats (bf16 hgA out) ----------------
__global__ __launch_bounds__(256) void gin_gemm1_kernel(
    const int* __restrict__ goffs, const int2* __restrict__ gpay,
    const ushort* __restrict__ xaggb, const float* __restrict__ bemb,
    const float* __restrict__ eps, const ushort* __restrict__ Bf,
    const float* __restrict__ bias, ushort* __restrict__ Cb,
    float* __restrict__ gsum, float* __restrict__ gsq)
{
    __shared__ ushort hg0s[64 * TSTR];
    __shared__ float ssum[128], ssq[128];
    int tid = threadIdx.x;
    if (tid < 128) { ssum[tid] = 0.f; ssq[tid] = 0.f; }
    {
        int row = tid >> 2;
        int fc = (tid & 3) * 32;
        int tn = blockIdx.x * 64 + row;
        float e1 = 1.0f + eps[0];
        float acc[32];
        const ushort* xo = xaggb + (size_t)tn * HH + fc;
        #pragma unroll
        for (int c = 0; c < 4; c++) {
            bf16x8 x = *(const bf16x8*)(xo + c * 8);
            #pragma unroll
            for (int j = 0; j < 8; j++)
                acc[c * 8 + j] = e1 * b2f((ushort)x[j]);
        }
        int beg = goffs[tn], end = goffs[tn + 1];
        for (int p = beg; p < end; p++) {
            int2 g = gpay[p];
            const ushort* xs = xaggb + (size_t)g.x * HH + fc;
            const float* bs = bemb + (size_t)g.y * HH + fc;
            #pragma unroll
            for (int c = 0; c < 4; c++) {
                bf16x8 x = *(const bf16x8*)(xs + c * 8);
                float4 b0 = *(const float4*)(bs + c * 8);
                float4 b1 = *(const float4*)(bs + c * 8 + 4);
                float bb[8] = {b0.x, b0.y, b0.z, b0.w, b1.x, b1.y, b1.z, b1.w};
                #pragma unroll
                for (int j = 0; j < 8; j++)
                    acc[c * 8 + j] += fmaxf(b2f((ushort)x[j]) + bb[j], 0.f);
            }
        }
        ushort* dst = hg0s + row * TSTR + fc;
        #pragma unroll
        for (int j = 0; j < 32; j++) dst[j] = f2b(acc[j]);
    }
    __syncthreads();
    int wave = tid >> 6, lane = tid & 63;
    int lm = lane & 15, lq = lane >> 4;
    int ak = lq * 8;
    bf16x8 a[4];
    #pragma unroll
    for (int kt = 0; kt < 4; kt++)
        a[kt] = *(const bf16x8*)&hg0s[(wave * 16 + lm) * TSTR + ak + kt * 32];
    f32x4 acc[8];
    #pragma unroll
    for (int i = 0; i < 8; i++) acc[i] = (f32x4){0.f, 0.f, 0.f, 0.f};
    const ushort* Bp = Bf + (size_t)lane * 8;
    #pragma unroll
    for (int nt = 0; nt < 8; nt++)
        #pragma unroll
        for (int kt = 0; kt < 4; kt++) {
            bf16x8 b = *(const bf16x8*)(Bp + ((size_t)(nt * 4 + kt)) * 512);
            acc[nt] = __builtin_amdgcn_mfma_f32_16x16x32_bf16(a[kt], b, acc[nt], 0, 0, 0);
        }
    int rbase = blockIdx.x * 64 + wave * 16 + lq * 4;
    #pragma unroll
    for (int nt = 0; nt < 8; nt++) {
        int col = nt * 16 + lm;
        float bs = bias[col];
        float ps = 0.f, pq = 0.f;
        #pragma unroll
        for (int r = 0; r < 4; r++) {
            float v = acc[nt][r] + bs;
            Cb[(size_t)(rbase + r) * 128 + col] = f2b(v);
            ps += v; pq += v * v;
        }
        atomicAdd(&ssum[col], ps);
        atomicAdd(&ssq[col], pq);
    }
    __syncthreads();
    if (tid < 128) {
        atomicAdd(&gsum[tid], ssum[tid]);
        atomicAdd(&gsq[tid], ssq[tid]);
    }
}

// ---------------- GIN gemm 2: A = relu(BN1(hgA bf16)); hgB(bf16) = A@B + bias, + stats ----------------
__global__ __launch_bounds__(256) void gemm_bn_stats_kernel(
    const ushort* __restrict__ Araw, const float* __restrict__ sum1,
    const float* __restrict__ sq1, const float* __restrict__ g1,
    const float* __restrict__ bb1, const ushort* __restrict__ Bf,
    const float* __restrict__ bias, ushort* __restrict__ Cb,
    float* __restrict__ gsum, float* __restrict__ gsq)
{
    __shared__ float ssum[128], ssq[128];
    int tid = threadIdx.x;
    if (tid < 128) { ssum[tid] = 0.f; ssq[tid] = 0.f; }
    __syncthreads();
    int wave = tid >> 6, lane = tid & 63;
    int m0 = (blockIdx.x * 4 + wave) * 16;
    int arow = m0 + (lane & 15);
    int ak = (lane >> 4) * 8;
    const float INV_NT = 1.0f / NT;
    bf16x8 a[4];
    const ushort* Ap = Araw + (size_t)arow * 128 + ak;
    #pragma unroll
    for (int kt = 0; kt < 4; kt++) {
        bf16x8 raw = *(const bf16x8*)(Ap + kt * 32);
        ushort ub[8];
        #pragma unroll
        for (int j = 0; j < 8; j++) {
            int k = ak + kt * 32 + j;
            float mu = sum1[k] * INV_NT;
            float var = sq1[k] * INV_NT - mu * mu;
            float inv = rsqrtf(var + 1e-5f);
            float w = fmaxf((b2f((ushort)raw[j]) - mu) * inv * g1[k] + bb1[k], 0.f);
            ub[j] = f2b(w);
        }
        a[kt] = *(bf16x8*)ub;
    }
    f32x4 acc[8];
    #pragma unroll
    for (int i = 0; i < 8; i++) acc[i] = (f32x4){0.f, 0.f, 0.f, 0.f};
    const ushort* Bp = Bf + (size_t)lane * 8;
    #pragma unroll
    for (int nt = 0; nt < 8; nt++)
        #pragma unroll
        for (int kt = 0; kt < 4; kt++) {
            bf16x8 b = *(const bf16x8*)(Bp + ((size_t)(nt * 4 + kt)) * 512);
            acc[nt] = __builtin_amdgcn_mfma_f32_16x16x32_bf16(a[kt], b, acc[nt], 0, 0, 0);
        }
    int col0 = lane & 15;
    int rbase = m0 + (lane >> 4) * 4;
    #pragma unroll
    for (int nt = 0; nt < 8; nt++) {
        int col = nt * 16 + col0;
        float bs = bias[col];
        float ps = 0.f, pq = 0.f;
        #pragma unroll
        for (int r = 0; r < 4; r++) {
            float v = acc[nt][r] + bs;
            Cb[(size_t)(rbase + r) * 128 + col] = f2b(v);
            ps += v; pq += v * v;
        }
        atomicAdd(&ssum[col], ps);
        atomicAdd(&ssq[col], pq);
    }
    __syncthreads();
    if (tid < 128) {
        atomicAdd(&gsum[tid], ssum[tid]);
        atomicAdd(&gsq[tid], ssq[tid]);
    }
}

// ---------------- fused CFConv tail: 3 chained GEMMs, coalesced epilogues ----------------
__global__ __launch_bounds__(256) void fused_lin_kernel(
    const ushort* __restrict__ aggb, const ushort* __restrict__ w2,
    const float* __restrict__ b2, const ushort* __restrict__ w3,
    const float* __restrict__ b3, const ushort* __restrict__ hgBb,
    const float* __restrict__ sum2, const float* __restrict__ sq2,
    const float* __restrict__ g2, const float* __restrict__ bb2,
    const int* __restrict__ cnb, const ushort* __restrict__ w1n,
    ushort* __restrict__ xb, ushort* __restrict__ h1b)
{
    __shared__ ushort t1s[4][16 * TSTR];
    __shared__ ushort t2s[4][16 * TSTR];
    int tid = threadIdx.x;
    int wave = tid >> 6, lane = tid & 63;
    int m0 = (blockIdx.x * 4 + wave) * 16;
    int lm = lane & 15;
    int lq = lane >> 4;
    ushort* T1 = t1s[wave];
    ushort* T2 = t2s[wave];
    const float INV_NT = 1.0f / NT;

    const ushort* Ap = aggb + (size_t)(m0 + lm) * 64 + lq * 8;
    bf16x8 a1[2];
    a1[0] = *(const bf16x8*)(Ap);
    a1[1] = *(const bf16x8*)(Ap + 32);
    f32x4 acc[8];
    #pragma unroll
    for (int i = 0; i < 8; i++) acc[i] = (f32x4){0.f, 0.f, 0.f, 0.f};
    {
        const ushort* Bp = w2 + (size_t)lane * 8;
        #pragma unroll
        for (int nt = 0; nt < 8; nt++)
            #pragma unroll
            for (int kt = 0; kt < 2; kt++) {
                bf16x8 b = *(const bf16x8*)(Bp + ((size_t)(nt * 2 + kt)) * 512);
                acc[nt] = __builtin_amdgcn_mfma_f32_16x16x32_bf16(a1[kt], b, acc[nt], 0, 0, 0);
            }
    }
    #pragma unroll
    for (int nt = 0; nt < 8; nt++) {
        int col = nt * 16 + lm;
        float bs = b2[col];
        #pragma unroll
        for (int r = 0; r < 4; r++) {
            float v = fmaxf(acc[nt][r] + bs, 0.f);
            T1[(lq * 4 + r) * TSTR + col] = f2b(v);
        }
    }
    __syncthreads();

    bf16x8 a2[4];
    #pragma unroll
    for (int kt = 0; kt < 4; kt++)
        a2[kt] = *(const bf16x8*)&T1[lm * TSTR + kt * 32 + lq * 8];
    __syncthreads();
    #pragma unroll
    for (int i = 0; i < 4; i++) {
        int idx = i * 64 + lane;
        int row = idx >> 4, ch = idx & 15;
        bf16x8 v = *(const bf16x8*)(xb + (size_t)(m0 + row) * HH + ch * 8);
        *(bf16x8*)&T1[row * TSTR + ch * 8] = v;
    }
    #pragma unroll
    for (int i = 0; i < 8; i++) acc[i] = (f32x4){0.f, 0.f, 0.f, 0.f};
    {
        const ushort* Bp = w3 + (size_t)lane * 8;
        #pragma unroll
        for (int nt = 0; nt < 8; nt++)
            #pragma unroll
            for (int kt = 0; kt < 4; kt++) {
                bf16x8 b = *(const bf16x8*)(Bp + ((size_t)(nt * 4 + kt)) * 512);
                acc[nt] = __builtin_amdgcn_mfma_f32_16x16x32_bf16(a2[kt], b, acc[nt], 0, 0, 0);
            }
    }
    int rbase = m0 + lq * 4;
    int cn[4];
    #pragma unroll
    for (int r = 0; r < 4; r++) cn[r] = cnb[rbase + r];
    #pragma unroll
    for (int nt = 0; nt < 8; nt++) {
        int col = nt * 16 + lm;
        float bs = b3[col];
        float mu2 = sum2[col] * INV_NT;
        float var2 = sq2[col] * INV_NT - mu2 * mu2;
        float sc2 = rsqrtf(var2 + 1e-5f) * g2[col];
        float sh2 = bb2[col] - mu2 * sc2;
        #pragma unroll
        for (int r = 0; r < 4; r++) {
            float v = acc[nt][r] + bs;
            v += b2f(T1[(lq * 4 + r) * TSTR + col]);
            v = fmaf(b2f(hgBb[(size_t)cn[r] * HH + col]), sc2, v + sh2);
            v = fmaxf(v, 0.f);
            T2[(lq * 4 + r) * TSTR + col] = f2b(v);
        }
    }
    __syncthreads();
    #pragma unroll
    for (int i = 0; i < 4; i++) {
        int idx = i * 64 + lane;
        int row = idx >> 4, ch = idx & 15;
        bf16x8 v = *(const bf16x8*)&T2[row * TSTR + ch * 8];
        *(bf16x8*)(xb + (size_t)(m0 + row) * HH + ch * 8) = v;
    }
    if (!w1n) return;
    __syncthreads();

    bf16x8 a3[4];
    #pragma unroll
    for (int kt = 0; kt < 4; kt++)
        a3[kt] = *(const bf16x8*)&T2[lm * TSTR + kt * 32 + lq * 8];
    f32x4 acc3[4];
    #pragma unroll
    for (int i = 0; i < 4; i++) acc3[i] = (f32x4){0.f, 0.f, 0.f, 0.f};
    {
        const ushort* Bp = w1n + (size_t)lane * 8;
        #pragma unroll
        for (int nt = 0; nt < 4; nt++)
            #pragma unroll
            for (int kt = 0; kt < 4; kt++) {
                bf16x8 b = *(const bf16x8*)(Bp + ((size_t)(nt * 4 + kt)) * 512);
                acc3[nt] = __builtin_amdgcn_mfma_f32_16x16x32_bf16(a3[kt], b, acc3[nt], 0, 0, 0);
            }
    }
    #pragma unroll
    for (int nt = 0; nt < 4; nt++) {
        int col = nt * 16 + lm;
        #pragma unroll
        for (int r = 0; r < 4; r++)
            T1[(lq * 4 + r) * TSTR + col] = f2b(acc3[nt][r]);
    }
    __syncthreads();
    #pragma unroll
    for (int i = 0; i < 2; i++) {
        int idx = i * 64 + lane;
        int row = idx >> 3, ch = idx & 7;
        bf16x8 v = *(const bf16x8*)&T1[row * TSTR + ch * 8];
        *(bf16x8*)(h1b + (size_t)(m0 + row) * FF + ch * 8) = v;
    }
}

// ---------------- output head with fused two-level max pool ----------------
__global__ __launch_bounds__(128) void out_layer_kernel(
    const ushort* __restrict__ xb, const float* __restrict__ w1,
    const float* __restrict__ b1, const float* __restrict__ w2,
    const float* __restrict__ b2, float* __restrict__ out)
{
    int m = blockIdx.x, f = threadIdx.x;
    const ushort* base = xb + (size_t)m * 256 * HH + f;
    float mx = -3.4e38f;
    for (int r = 0; r < 256; r++)
        mx = fmaxf(mx, b2f(base[(size_t)r * HH]));
    __shared__ float xs[128];
    xs[f] = mx;
    __syncthreads();
    float acc = b1[f];
    for (int k = 0; k < 128; k++) acc = fmaf(xs[k], w1[k * HH + f], acc);
    acc = fmaxf(acc, 0.f) * w2[f];
    __shared__ float red[128];
    red[f] = acc;
    __syncthreads();
    for (int off = 64; off > 0; off >>= 1) {
        if (f < off) red[f] += red[f + off];
        __syncthreads();
    }
    if (f == 0) out[m] = red[0] + b2[0];
}

extern "C" void kernel_launch(void* const* d_in, const int* in_sizes, int n_in,
                              void* d_out, int out_size, void* d_ws, size_t ws_size,
                              hipStream_t stream)
{
    const int*   x_topo    = (const int*)d_in[0];
    const float* pos       = (const float*)d_in[1];
    const int*   eic       = (const int*)d_in[2];
    const int*   eig       = (const int*)d_in[3];
    const int*   eattr     = (const int*)d_in[4];
    const int*   cnb       = (const int*)d_in[5];
    const float* atom_emb  = (const float*)d_in[8];
    const float* cf_lin1_w = (const float*)d_in[9];
    const float* cf_mlp_w1 = (const float*)d_in[10];
    const float* cf_mlp_b1 = (const float*)d_in[11];
    const float* cf_mlp_w2 = (const float*)d_in[12];
    const float* cf_mlp_b2 = (const float*)d_in[13];
    const float* cf_lin2_w = (const float*)d_in[14];
    const float* cf_lin2_b = (const float*)d_in[15];
    const float* lin_w     = (const float*)d_in[16];
    const float* lin_b     = (const float*)d_in[17];
    const float* bond_emb  = (const float*)d_in[18];
    const float* gin_w1    = (const float*)d_in[19];
    const float* gin_b1    = (const float*)d_in[20];
    const float* gin_w2    = (const float*)d_in[21];
    const float* gin_b2    = (const float*)d_in[22];
    const float* gin_bn_g  = (const float*)d_in[23];
    const float* gin_bn_b  = (const float*)d_in[24];
    const float* bn_g      = (const float*)d_in[25];
    const float* bn_b      = (const float*)d_in[26];
    const float* gin_eps   = (const float*)d_in[27];
    const float* out_w1    = (const float*)d_in[28];
    const float* out_b1    = (const float*)d_in[29];
    const float* out_w2    = (const float*)d_in[30];
    const float* out_b2    = (const float*)d_in[31];
    float* out = (float*)d_out;

    char* wsb = (char*)d_ws;
    size_t off = 0;
    auto alloc = [&](size_t nbytes) -> void* {
        void* p = (void*)(wsb + off);
        off += (nbytes + 255) & ~(size_t)255;
        return p;
    };
    ushort* xb      = (ushort*)alloc((size_t)NN * HH * 2);
    ushort* h1b     = (ushort*)alloc((size_t)NN * FF * 2);
    ushort* aggb    = (ushort*)alloc((size_t)NN * FF * 2);
    ushort* xaggb   = (ushort*)alloc((size_t)NT * HH * 2);
    ushort* hgA     = (ushort*)alloc((size_t)NT * HH * 2);
    ushort* hgB     = (ushort*)alloc((size_t)NT * HH * 2);
    float*  table_all  = (float*)alloc((size_t)4 * TBL * 64 * 4);
    ushort2* table2_all = (ushort2*)alloc((size_t)4 * TBL * 64 * 4);
    // stats + cntA + degC + ovf_cnt adjacent -> single memset
    float*  stats   = (float*)alloc((size_t)4 * 4 * 128 * 4);     // 8 KB
    int*    cntA    = (int*)alloc((size_t)NN * 4);                // 256 KB
    int*    degC    = (int*)alloc((size_t)NT * 4);                // 32 KB
    int*    ovf_cnt = (int*)alloc(256);                           // 256 B
    int*    offsC   = (int*)alloc((NT + 1) * 4);
    int*    curC    = (int*)alloc(NT * 4);
    int*    pay_pad = (int*)alloc((size_t)NN * CAP * 4);          // 8 MB padded CSR
    int2*   ovf     = (int2*)alloc((size_t)OVF_CAP * 8);
    int2*   gpay    = (int2*)alloc((size_t)EG * 8);
    ushort* w1f     = (ushort*)alloc((size_t)4 * HH * FF * 2);
    ushort* w2f     = (ushort*)alloc((size_t)4 * FF * HH * 2);
    ushort* wlf     = (ushort*)alloc((size_t)4 * HH * HH * 2);
    ushort* gw1f    = (ushort*)alloc((size_t)4 * HH * HH * 2);
    ushort* gw2f    = (ushort*)alloc((size_t)4 * HH * HH * 2);

    // --- single memset covering stats + cntA + degC + ovf_cnt (adjacent, 256B-aligned) ---
    hipMemsetAsync(stats, 0,
        ((size_t)4 * 4 * 128 * 4 + 255 & ~(size_t)255) +
        ((size_t)NN * 4 + 255 & ~(size_t)255) +
        ((size_t)NT * 4 + 255 & ~(size_t)255) + 256, stream);
    // --- sentinel fill of padded CSR (must complete before setup's fused scatter) ---
    hipMemsetD32Async((hipDeviceptr_t)pay_pad, SENT, (size_t)NN * CAP, stream);

    // --- mega setup: scatter(nt) + ghist + embed + Wf-table + weight prep ---
    setup_kernel<<<SETUP_B4, 256, 0, stream>>>(
        eic, cnb, eig, pos, atom_emb, x_topo, degC, xb, cntA, pay_pad, ovf_cnt, ovf,
        cf_mlp_w1, cf_mlp_b1, cf_mlp_w2, cf_mlp_b2, table_all,
        cf_lin1_w, cf_lin2_w, lin_w, gin_w1, gin_w2, w1f, w2f, wlf, gw1f, gw2f);
    scanC_kernel<<<1, 256, 0, stream>>>(degC, offsC, curC);
    scatter_graph_kernel<<<EG / 256, 256, 0, stream>>>(eig, eattr, curC, gpay);
    pack_table_kernel<<<4 * TBL * 64 / 256, 256, 0, stream>>>(table_all, table2_all);

    // initial h1b = xb @ cf_lin1_w[0]
    gemm_bf16_kernel<<<NN / 64, 256, 0, stream>>>(xb, w1f, h1b);

    for (int l = 0; l < 4; l++) {
        const ushort2* table2 = table2_all + (size_t)l * TBL * 64;
        float* sum1 = stats + (size_t)l * 512;
        float* sq1  = sum1 + 128;
        float* sum2 = sum1 + 256;
        float* sq2  = sum1 + 384;
        edge_xagg_kernel<<<NEB + NT * HH / 256, 256, 0, stream>>>(
            cntA, pay_pad, ovf_cnt, ovf, table2, h1b, aggb, xb, xaggb);
        gin_gemm1_kernel<<<NT / 64, 256, 0, stream>>>(
            offsC, gpay, xaggb, bond_emb + (size_t)l * 10 * HH, gin_eps + l,
            gw1f + (size_t)l * HH * HH, gin_b1 + (size_t)l * HH, hgA, sum1, sq1);
        gemm_bn_stats_kernel<<<NT / 64, 256, 0, stream>>>(
            hgA, sum1, sq1, gin_bn_g + (size_t)l * HH, gin_bn_b + (size_t)l * HH,
            gw2f + (size_t)l * HH * HH, gin_b2 + (size_t)l * HH, hgB, sum2, sq2);
        fused_lin_kernel<<<NN / 64, 256, 0, stream>>>(
            aggb, w2f + (size_t)l * FF * HH, cf_lin2_b + (size_t)l * HH,
            wlf + (size_t)l * HH * HH, lin_b + (size_t)l * HH,
            hgB, sum2, sq2, bn_g + (size_t)l * HH, bn_b + (size_t)l * HH,
            cnb, (l < 3) ? (w1f + (size_t)(l + 1) * HH * FF) : nullptr,
            xb, h1b);
    }

    out_layer_kernel<<<MM, 128, 0, stream>>>(xb, out_w1, out_b1, out_w2, out_b2, out);
}

// Round 6
// 637.058 us; speedup vs baseline: 1.0034x; 1.0034x over previous
//
#include <hip/hip_runtime.h>
#include <hip/hip_bf16.h>

#define EC 1048576   // conformer edges
#define NN 65536     // conformer nodes
#define NT 8192      // topo nodes
#define MM 256
#define HH 128
#define FF 64
#define GG 50
#define EG 32768     // graph edges

#define TBL 2048            // Wf table entries per layer (512KB/layer -> L2-resident)
#define TBL_SHIFT 11
#define TRANGE 14.0f

#define CAP 32              // padded-CSR slots per node (Poisson(16); overflow list handles tail)
#define OVF_CAP 8192        // overflow list capacity (writes/reads hard-bounded)
#define NEB (NN * 64 / 256)     // edge-agg blocks in merged dispatch

// sentinel pay: table index 2047 (never produced by real edges: i0<=2046), fr=0, row=0
// table2[2047] is forced to {0,0} -> contribution exactly 0 without any masking
#define SENT 0xFFE00000

constexpr float STEP = 10.0f / 49.0f;
constexpr float GC = -0.5f / (STEP * STEP);

typedef __attribute__((ext_vector_type(8))) short bf16x8;
typedef __attribute__((ext_vector_type(4))) float f32x4;

__device__ __forceinline__ ushort f2b(float v) {
    __hip_bfloat16 h = __float2bfloat16(v);
    return *(ushort*)&h;
}
__device__ __forceinline__ float b2f(ushort u) {
    return __uint_as_float(((unsigned)u) << 16);
}

// ---------------- weight prep helper ----------------
__device__ __forceinline__ void prep_one(
    const float* __restrict__ W, ushort* __restrict__ Wf, int K, int N, int idx)
{
    int sz = K * N;
    int l = idx / sz;
    int t = idx - l * sz;
    int j = t & 7;
    int lane = (t >> 3) & 63;
    int rest = t >> 9;
    int KTl = K >> 5;
    int kt = rest % KTl;
    int nt = rest / KTl;
    int k = kt * 32 + (lane >> 4) * 8 + j;
    int n = nt * 16 + (lane & 15);
    Wf[idx] = f2b(W[(size_t)l * sz + (size_t)k * N + n]);
}

// ---------------- mega setup: scatter + ghist + embed + Wf-table + weight prep ----------------
// Scatter branch: 4 edges/thread -> 4 independent atomicAdd chains in flight per lane
// (the scatter is capped by outstanding far-atomic requests, not BW or VALU).
// pay_pad sentinel-filled + cntA/ovf_cnt zeroed BEFORE this kernel.
#define SETUP_B0 (EC / 1024)
#define SETUP_B1 (SETUP_B0 + EG / 256)
#define SETUP_B2 (SETUP_B1 + NN * HH / 8 / 256)
#define SETUP_B3 (SETUP_B2 + 4 * TBL / 4)
#define SETUP_B4 (SETUP_B3 + 1024)
__global__ __launch_bounds__(256) void setup_kernel(
    const int* __restrict__ eic, const int* __restrict__ cnb,
    const int* __restrict__ eig, const float* __restrict__ pos,
    const float* __restrict__ emb, const int* __restrict__ xtopo,
    int* __restrict__ degC, ushort* __restrict__ xb,
    int* __restrict__ cntA, int* __restrict__ pay_pad,
    int* __restrict__ ovf_cnt, int2* __restrict__ ovf,
    const float* __restrict__ mw1, const float* __restrict__ mb1,
    const float* __restrict__ mw2, const float* __restrict__ mb2,
    float* __restrict__ table_all,
    const float* __restrict__ cf_lin1_w, const float* __restrict__ cf_lin2_w,
    const float* __restrict__ lin_w, const float* __restrict__ gin_w1,
    const float* __restrict__ gin_w2,
    ushort* __restrict__ w1f, ushort* __restrict__ w2f, ushort* __restrict__ wlf,
    ushort* __restrict__ gw1f, ushort* __restrict__ gw2f)
{
    int b = blockIdx.x, tid = threadIdx.x;
    if (b < SETUP_B0) {
        // 4 edges per thread: int4-coalesced edge loads, 4 independent atomic+store chains
        int e0 = (b * 256 + tid) * 4;
        int4 r4 = *(const int4*)(eic + e0);
        int4 c4 = *(const int4*)(eic + EC + e0);
        int rr[4] = {r4.x, r4.y, r4.z, r4.w};
        int cc[4] = {c4.x, c4.y, c4.z, c4.w};
        int pay[4];
        #pragma unroll
        for (int q = 0; q < 4; q++) {
            int r = rr[q], c = cc[q];
            float dx = pos[r*3+0] - pos[c*3+0];
            float dy = pos[r*3+1] - pos[c*3+1];
            float dz = pos[r*3+2] - pos[c*3+2];
            float w = sqrtf(dx*dx + dy*dy + dz*dz + 1e-12f);
            float u = fminf(w * ((TBL - 1) / TRANGE), 2046.96875f);
            pay[q] = (((int)(u * 32.0f)) << 16) | (r & 0xFFFF);   // 11.5 fixed point | row
        }
        int slot[4];
        #pragma unroll
        for (int q = 0; q < 4; q++)        // 4 independent far atomics in flight
            slot[q] = atomicAdd(&cntA[cc[q]], 1);
        #pragma unroll
        for (int q = 0; q < 4; q++) {
            if (slot[q] < CAP) {
                pay_pad[cc[q] * CAP + slot[q]] = pay[q];
            } else {
                int o = atomicAdd(ovf_cnt, 1);
                if (o < OVF_CAP) ovf[o] = make_int2(cc[q], pay[q]);   // hard bound
            }
        }
    } else if (b < SETUP_B1) {
        atomicAdd(&degC[eig[EG + (b - SETUP_B0) * 256 + tid]], 1);
    } else if (b < SETUP_B2) {
        // vectorized embedding broadcast: 8 features per thread
        int idx = (b - SETUP_B1) * 256 + tid;   // 0 .. NN*HH/8
        int n = idx >> 4;
        int f8 = (idx & 15) << 3;
        const float* e = emb + (size_t)xtopo[cnb[n]] * HH + f8;
        float4 v0 = *(const float4*)e;
        float4 v1 = *(const float4*)(e + 4);
        ushort u[8] = {f2b(v0.x), f2b(v0.y), f2b(v0.z), f2b(v0.w),
                       f2b(v1.x), f2b(v1.y), f2b(v1.z), f2b(v1.w)};
        *(bf16x8*)(xb + ((size_t)idx << 3)) = *(const bf16x8*)u;
    } else if (b < SETUP_B3) {
        // Wf table: 4 entries per block, one per wave
        int entry = (b - SETUP_B2) * 4 + (tid >> 6);
        int l = entry >> TBL_SHIFT;
        int p = entry & (TBL - 1);
        int lane = tid & 63;
        int wv = tid >> 6;
        const float* w1 = mw1 + (size_t)l * GG * FF;
        const float* b1 = mb1 + (size_t)l * FF;
        const float* w2 = mw2 + (size_t)l * FF * FF;
        const float* b2 = mb2 + (size_t)l * FF;
        float w = p * (TRANGE / (TBL - 1));
        float t = b1[lane];
        for (int g = 0; g < GG; g++) {
            float d = w - g * STEP;
            float ea = __expf(GC * d * d);
            t = fmaf(ea, w1[g * 64 + lane], t);
        }
        __shared__ float ts[4][64];
        ts[wv][lane] = fmaxf(t, 0.f);
        __syncthreads();
        float wf = b2[lane];
        for (int i = 0; i < 64; i++)
            wf = fmaf(ts[wv][i], w2[i * 64 + lane], wf);
        float cw = 0.5f * (__cosf(w * (3.14159265358979323846f / 10.0f)) + 1.0f);
        table_all[((size_t)l * TBL + p) * 64 + lane] = wf * cw;
    } else {
        int pb = b - SETUP_B3;
        if (pb < 128)       prep_one(cf_lin1_w, w1f, HH, FF, pb * 256 + tid);
        else if (pb < 256)  prep_one(cf_lin2_w, w2f, FF, HH, (pb - 128) * 256 + tid);
        else if (pb < 512)  prep_one(lin_w, wlf, HH, HH, (pb - 256) * 256 + tid);
        else if (pb < 768)  prep_one(gin_w1, gw1f, HH, HH, (pb - 512) * 256 + tid);
        else                prep_one(gin_w2, gw2f, HH, HH, (pb - 768) * 256 + tid);
    }
}

// ---------------- single-block exclusive scan for chain C (NT bins) ----------------
__global__ __launch_bounds__(256) void scanC_kernel(
    const int* __restrict__ degC, int* __restrict__ offsC, int* __restrict__ curC)
{
    __shared__ int s[256];
    __shared__ int base;
    int tid = threadIdx.x;
    if (tid == 0) base = 0;
    __syncthreads();
    for (int c = 0; c < NT / 256; c++) {
        int v = degC[c * 256 + tid];
        s[tid] = v;
        __syncthreads();
        for (int off = 1; off < 256; off <<= 1) {
            int t = (tid >= off) ? s[tid - off] : 0;
            __syncthreads();
            s[tid] += t;
            __syncthreads();
        }
        int excl = s[tid] - v + base;
        offsC[c * 256 + tid] = excl;
        curC[c * 256 + tid] = excl;
        __syncthreads();
        if (tid == 255) base += s[255];
        __syncthreads();
    }
    if (tid == 0) offsC[NT] = EG;
}

// ---------------- graph-edge scatter only ----------------
__global__ __launch_bounds__(256) void scatter_graph_kernel(
    const int* __restrict__ eig, const int* __restrict__ eattr,
    int* __restrict__ curC, int2* __restrict__ gpay)
{
    int e = blockIdx.x * 256 + threadIdx.x;
    int p = atomicAdd(&curC[eig[EG + e]], 1);
    gpay[p] = make_int2(eig[e], eattr[e]);
}

// pack fp32 table -> {t0, dt/32} bf16 pair; entry TBL-1 forced to {0,0} (sentinel target)
__global__ __launch_bounds__(256) void pack_table_kernel(
    const float* __restrict__ table_all, ushort2* __restrict__ table2_all)
{
    int idx = blockIdx.x * 256 + threadIdx.x;   // 4*TBL*64
    int f = idx & 63;
    int rest = idx >> 6;
    int i = rest & (TBL - 1);
    int l = rest >> TBL_SHIFT;
    if (i == TBL - 1) {
        table2_all[idx] = make_ushort2(0, 0);
        return;
    }
    const float* T = table_all + ((size_t)l * TBL) * 64;
    float t0 = T[(size_t)i * 64 + f];
    float t1 = T[(size_t)(i + 1) * 64 + f];
    // dt prescaled by 1/32 (exact pow2 shift in bf16): wf = fmaf(dts, (float)frac5, t0)
    table2_all[idx] = make_ushort2(f2b(t0), f2b((t1 - t0) * 0.03125f));
}

// ---------------- plain bf16 MFMA GEMM (initial h1b only), N=64 K=128 ----------------
__global__ __launch_bounds__(256) void gemm_bf16_kernel(
    const ushort* __restrict__ A, const ushort* __restrict__ Bf,
    ushort* __restrict__ Cb)
{
    int tid = threadIdx.x;
    int wave = tid >> 6, lane = tid & 63;
    int m0 = (blockIdx.x * 4 + wave) * 16;
    int arow = m0 + (lane & 15);
    int ak = (lane >> 4) * 8;
    bf16x8 a[4];
    const ushort* Ap = A + (size_t)arow * 128 + ak;
    #pragma unroll
    for (int kt = 0; kt < 4; kt++)
        a[kt] = *(const bf16x8*)(Ap + kt * 32);
    f32x4 acc[4];
    #pragma unroll
    for (int i = 0; i < 4; i++) acc[i] = (f32x4){0.f, 0.f, 0.f, 0.f};
    const ushort* Bp = Bf + (size_t)lane * 8;
    #pragma unroll
    for (int nt = 0; nt < 4; nt++)
        #pragma unroll
        for (int kt = 0; kt < 4; kt++) {
            bf16x8 b = *(const bf16x8*)(Bp + ((size_t)(nt * 4 + kt)) * 512);
            acc[nt] = __builtin_amdgcn_mfma_f32_16x16x32_bf16(a[kt], b, acc[nt], 0, 0, 0);
        }
    int col0 = lane & 15;
    int rbase = m0 + (lane >> 4) * 4;
    #pragma unroll
    for (int nt = 0; nt < 4; nt++) {
        int col = nt * 16 + col0;
        #pragma unroll
        for (int r = 0; r < 4; r++)
            Cb[(size_t)(rbase + r) * 64 + col] = f2b(acc[nt][r]);
    }
}

// 8-wide edge batch, NO masking (sentinel pays -> exact 0 contribution).
// pp is wave-uniform; pays forced to SGPR via readfirstlane so all the
// unpack/address math runs on the SALU pipe; gathers are saddr+voffset32.
#define EDGE8(BASE) { \
    int pq[8]; \
    { int4 q0 = *(const int4*)(pp + BASE); \
      int4 q1 = *(const int4*)(pp + BASE + 4); \
      pq[0]=__builtin_amdgcn_readfirstlane(q0.x); \
      pq[1]=__builtin_amdgcn_readfirstlane(q0.y); \
      pq[2]=__builtin_amdgcn_readfirstlane(q0.z); \
      pq[3]=__builtin_amdgcn_readfirstlane(q0.w); \
      pq[4]=__builtin_amdgcn_readfirstlane(q1.x); \
      pq[5]=__builtin_amdgcn_readfirstlane(q1.y); \
      pq[6]=__builtin_amdgcn_readfirstlane(q1.z); \
      pq[7]=__builtin_amdgcn_readfirstlane(q1.w); } \
    float h[8]; \
    _Pragma("unroll") \
    for (int q = 0; q < 8; q++) \
        h[q] = b2f(*(const ushort*)(h1c + ((((unsigned)(pq[q] & 0xFFFF)) << 7) + lane2))); \
    unsigned tt[8]; \
    _Pragma("unroll") \
    for (int q = 0; q < 8; q++) \
        tt[q] = *(const unsigned*)(tbc + (((((unsigned)pq[q]) >> 21) << 8) + lane4)); \
    _Pragma("unroll") \
    for (int q = 0; q < 8; q++) { \
        float fr = (float)((unsigned)((pq[q] >> 16) & 31)); \
        float t0 = __uint_as_float(tt[q] << 16); \
        float dts = __uint_as_float(tt[q] & 0xFFFF0000u); \
        float wf = fmaf(dts, fr, t0); \
        if (q & 1) acc1 = fmaf(h[q], wf, acc1); else acc0 = fmaf(h[q], wf, acc0); \
    } }

// ---------------- merged: padded-CSR edge aggregation + closed-form xagg max ----------------
__global__ __launch_bounds__(256) void edge_xagg_kernel(
    const int* __restrict__ cntA, const int* __restrict__ pay_pad,
    const int* __restrict__ ovf_cnt, const int2* __restrict__ ovf,
    const ushort2* __restrict__ table2, const ushort* __restrict__ h1b,
    ushort* __restrict__ aggb,
    const ushort* __restrict__ xb, ushort* __restrict__ xaggb)
{
    int tid = threadIdx.x;
    if (blockIdx.x < NEB) {
        int lane = tid & 63;
        int node = __builtin_amdgcn_readfirstlane((blockIdx.x * 256 + tid) >> 6);
        unsigned lane2 = (unsigned)lane * 2;
        unsigned lane4 = (unsigned)lane * 4;
        const char* h1c = (const char*)h1b;
        const char* tbc = (const char*)table2;
        int deg = cntA[node];
        int n1 = min(deg, CAP);
        const int* pp = pay_pad + (size_t)node * CAP;
        float acc0 = 0.f, acc1 = 0.f;
        EDGE8(0);
        if (n1 > 8) {
            EDGE8(8);
            if (n1 > 16) {
                EDGE8(16);
                if (n1 > 24) EDGE8(24);
            }
        }
        float acc = acc0 + acc1;
        if (deg > CAP) {   // rare overflow path (Poisson(16) tail): scan tiny list
            int no = min(*ovf_cnt, OVF_CAP);   // hard bound
            for (int j = 0; j < no; j++) {
                int2 o = ovf[j];
                if (o.x == node) {
                    unsigned uf = (unsigned)o.y >> 16;
                    int i0 = uf >> 5;
                    float fr = (float)(uf & 31);
                    ushort2 ttv = table2[(size_t)i0 * 64 + lane];
                    acc = fmaf(b2f(h1b[(size_t)(o.y & 0xFFFF) * 64 + lane]),
                               fmaf(b2f(ttv.y), fr, b2f(ttv.x)), acc);
                }
            }
        }
        aggb[(size_t)node * 64 + lane] = f2b(acc);
    } else {
        int idx = (blockIdx.x - NEB) * 256 + tid;   // NT*HH
        int tn = idx >> 7, f = idx & 127;
        int m = tn >> 5, a = tn & 31;
        const ushort* base = xb + ((size_t)((m << 8) + a)) * HH + f;
        float mx = -3.4e38f;
        #pragma unroll
        for (int k = 0; k < 8; k++)
            mx = fmaxf(mx, b2f(base[(size_t)(k << 5) * HH]));
        xaggb[idx] = f2b(mx);
    }
}

#define TSTR 136

// ---------------- GIN GEMM1 with fused magg/hg0 tile build + stats (bf16 hgA out) ----------------
__global__ __launch_bounds__(256) void gin_gemm1_kernel(
    const int* __restrict__ goffs, const int2* __restrict__ gpay,
    const ushort* __restrict__ xaggb, const float* __restrict__ bemb,
    const float* __restrict__ eps, const ushort* __restrict__ Bf,
    const float* __restrict__ bias, ushort* __restrict__ Cb,
    float* __restrict__ gsum, float* __restrict__ gsq)
{
    __shared__ ushort hg0s[64 * TSTR];
    __shared__ float ssum[128], ssq[128];
    int tid = threadIdx.x;
    if (tid < 128) { ssum[tid] = 0.f; ssq[tid] = 0.f; }
    {
        int row = tid >> 2;
        int fc = (tid & 3) * 32;
        int tn = blockIdx.x * 64 + row;
        float e1 = 1.0f + eps[0];
        float acc[32];
        const ushort* xo = xaggb + (size_t)tn * HH + fc;
        #pragma unroll
        for (int c = 0; c < 4; c++) {
            bf16x8 x = *(const bf16x8*)(xo + c * 8);
            #pragma unroll
            for (int j = 0; j < 8; j++)
                acc[c * 8 + j] = e1 * b2f((ushort)x[j]);
        }
        int beg = goffs[tn], end = goffs[tn + 1];
        for (int p = beg; p < end; p++) {
            int2 g = gpay[p];
            const ushort* xs = xaggb + (size_t)g.x * HH + fc;
            const float* bs = bemb + (size_t)g.y * HH + fc;
            #pragma unroll
            for (int c = 0; c < 4; c++) {
                bf16x8 x = *(const bf16x8*)(xs + c * 8);
                float4 b0 = *(const float4*)(bs + c * 8);
                float4 b1 = *(const float4*)(bs + c * 8 + 4);
                float bb[8] = {b0.x, b0.y, b0.z, b0.w, b1.x, b1.y, b1.z, b1.w};
                #pragma unroll
                for (int j = 0; j < 8; j++)
                    acc[c * 8 + j] += fmaxf(b2f((ushort)x[j]) + bb[j], 0.f);
            }
        }
        ushort* dst = hg0s + row * TSTR + fc;
        #pragma unroll
        for (int j = 0; j < 32; j++) dst[j] = f2b(acc[j]);
    }
    __syncthreads();
    int wave = tid >> 6, lane = tid & 63;
    int lm = lane & 15, lq = lane >> 4;
    int ak = lq * 8;
    bf16x8 a[4];
    #pragma unroll
    for (int kt = 0; kt < 4; kt++)
        a[kt] = *(const bf16x8*)&hg0s[(wave * 16 + lm) * TSTR + ak + kt * 32];
    f32x4 acc[8];
    #pragma unroll
    for (int i = 0; i < 8; i++) acc[i] = (f32x4){0.f, 0.f, 0.f, 0.f};
    const ushort* Bp = Bf + (size_t)lane * 8;
    #pragma unroll
    for (int nt = 0; nt < 8; nt++)
        #pragma unroll
        for (int kt = 0; kt < 4; kt++) {
            bf16x8 b = *(const bf16x8*)(Bp + ((size_t)(nt * 4 + kt)) * 512);
            acc[nt] = __builtin_amdgcn_mfma_f32_16x16x32_bf16(a[kt], b, acc[nt], 0, 0, 0);
        }
    int rbase = blockIdx.x * 64 + wave * 16 + lq * 4;
    #pragma unroll
    for (int nt = 0; nt < 8; nt++) {
        int col = nt * 16 + lm;
        float bs = bias[col];
        float ps = 0.f, pq = 0.f;
        #pragma unroll
        for (int r = 0; r < 4; r++) {
            float v = acc[nt][r] + bs;
            Cb[(size_t)(rbase + r) * 128 + col] = f2b(v);
            ps += v; pq += v * v;
        }
        atomicAdd(&ssum[col], ps);
        atomicAdd(&ssq[col], pq);
    }
    __syncthreads();
    if (tid < 128) {
        atomicAdd(&gsum[tid], ssum[tid]);
        atomicAdd(&gsq[tid], ssq[tid]);
    }
}

// ---------------- GIN gemm 2: A = relu(BN1(hgA bf16)); hgB(bf16) = A@B + bias, + stats ----------------
__global__ __launch_bounds__(256) void gemm_bn_stats_kernel(
    const ushort* __restrict__ Araw, const float* __restrict__ sum1,
    const float* __restrict__ sq1, const float* __restrict__ g1,
    const float* __restrict__ bb1, const ushort* __restrict__ Bf,
    const float* __restrict__ bias, ushort* __restrict__ Cb,
    float* __restrict__ gsum, float* __restrict__ gsq)
{
    __shared__ float ssum[128], ssq[128];
    int tid = threadIdx.x;
    if (tid < 128) { ssum[tid] = 0.f; ssq[tid] = 0.f; }
    __syncthreads();
    int wave = tid >> 6, lane = tid & 63;
    int m0 = (blockIdx.x * 4 + wave) * 16;
    int arow = m0 + (lane & 15);
    int ak = (lane >> 4) * 8;
    const float INV_NT = 1.0f / NT;
    bf16x8 a[4];
    const ushort* Ap = Araw + (size_t)arow * 128 + ak;
    #pragma unroll
    for (int kt = 0; kt < 4; kt++) {
        bf16x8 raw = *(const bf16x8*)(Ap + kt * 32);
        ushort ub[8];
        #pragma unroll
        for (int j = 0; j < 8; j++) {
            int k = ak + kt * 32 + j;
            float mu = sum1[k] * INV_NT;
            float var = sq1[k] * INV_NT - mu * mu;
            float inv = rsqrtf(var + 1e-5f);
            float w = fmaxf((b2f((ushort)raw[j]) - mu) * inv * g1[k] + bb1[k], 0.f);
            ub[j] = f2b(w);
        }
        a[kt] = *(bf16x8*)ub;
    }
    f32x4 acc[8];
    #pragma unroll
    for (int i = 0; i < 8; i++) acc[i] = (f32x4){0.f, 0.f, 0.f, 0.f};
    const ushort* Bp = Bf + (size_t)lane * 8;
    #pragma unroll
    for (int nt = 0; nt < 8; nt++)
        #pragma unroll
        for (int kt = 0; kt < 4; kt++) {
            bf16x8 b = *(const bf16x8*)(Bp + ((size_t)(nt * 4 + kt)) * 512);
            acc[nt] = __builtin_amdgcn_mfma_f32_16x16x32_bf16(a[kt], b, acc[nt], 0, 0, 0);
        }
    int col0 = lane & 15;
    int rbase = m0 + (lane >> 4) * 4;
    #pragma unroll
    for (int nt = 0; nt < 8; nt++) {
        int col = nt * 16 + col0;
        float bs = bias[col];
        float ps = 0.f, pq = 0.f;
        #pragma unroll
        for (int r = 0; r < 4; r++) {
            float v = acc[nt][r] + bs;
            Cb[(size_t)(rbase + r) * 128 + col] = f2b(v);
            ps += v; pq += v * v;
        }
        atomicAdd(&ssum[col], ps);
        atomicAdd(&ssq[col], pq);
    }
    __syncthreads();
    if (tid < 128) {
        atomicAdd(&gsum[tid], ssum[tid]);
        atomicAdd(&gsq[tid], ssq[tid]);
    }
}

// ---------------- fused CFConv tail: 3 chained GEMMs, coalesced epilogues ----------------
__global__ __launch_bounds__(256) void fused_lin_kernel(
    const ushort* __restrict__ aggb, const ushort* __restrict__ w2,
    const float* __restrict__ b2, const ushort* __restrict__ w3,
    const float* __restrict__ b3, const ushort* __restrict__ hgBb,
    const float* __restrict__ sum2, const float* __restrict__ sq2,
    const float* __restrict__ g2, const float* __restrict__ bb2,
    const int* __restrict__ cnb, const ushort* __restrict__ w1n,
    ushort* __restrict__ xb, ushort* __restrict__ h1b)
{
    __shared__ ushort t1s[4][16 * TSTR];
    __shared__ ushort t2s[4][16 * TSTR];
    int tid = threadIdx.x;
    int wave = tid >> 6, lane = tid & 63;
    int m0 = (blockIdx.x * 4 + wave) * 16;
    int lm = lane & 15;
    int lq = lane >> 4;
    ushort* T1 = t1s[wave];
    ushort* T2 = t2s[wave];
    const float INV_NT = 1.0f / NT;

    const ushort* Ap = aggb + (size_t)(m0 + lm) * 64 + lq * 8;
    bf16x8 a1[2];
    a1[0] = *(const bf16x8*)(Ap);
    a1[1] = *(const bf16x8*)(Ap + 32);
    f32x4 acc[8];
    #pragma unroll
    for (int i = 0; i < 8; i++) acc[i] = (f32x4){0.f, 0.f, 0.f, 0.f};
    {
        const ushort* Bp = w2 + (size_t)lane * 8;
        #pragma unroll
        for (int nt = 0; nt < 8; nt++)
            #pragma unroll
            for (int kt = 0; kt < 2; kt++) {
                bf16x8 b = *(const bf16x8*)(Bp + ((size_t)(nt * 2 + kt)) * 512);
                acc[nt] = __builtin_amdgcn_mfma_f32_16x16x32_bf16(a1[kt], b, acc[nt], 0, 0, 0);
            }
    }
    #pragma unroll
    for (int nt = 0; nt < 8; nt++) {
        int col = nt * 16 + lm;
        float bs = b2[col];
        #pragma unroll
        for (int r = 0; r < 4; r++) {
            float v = fmaxf(acc[nt][r] + bs, 0.f);
            T1[(lq * 4 + r) * TSTR + col] = f2b(v);
        }
    }
    __syncthreads();

    bf16x8 a2[4];
    #pragma unroll
    for (int kt = 0; kt < 4; kt++)
        a2[kt] = *(const bf16x8*)&T1[lm * TSTR + kt * 32 + lq * 8];
    __syncthreads();
    #pragma unroll
    for (int i = 0; i < 4; i++) {
        int idx = i * 64 + lane;
        int row = idx >> 4, ch = idx & 15;
        bf16x8 v = *(const bf16x8*)(xb + (size_t)(m0 + row) * HH + ch * 8);
        *(bf16x8*)&T1[row * TSTR + ch * 8] = v;
    }
    #pragma unroll
    for (int i = 0; i < 8; i++) acc[i] = (f32x4){0.f, 0.f, 0.f, 0.f};
    {
        const ushort* Bp = w3 + (size_t)lane * 8;
        #pragma unroll
        for (int nt = 0; nt < 8; nt++)
            #pragma unroll
            for (int kt = 0; kt < 4; kt++) {
                bf16x8 b = *(const bf16x8*)(Bp + ((size_t)(nt * 4 + kt)) * 512);
                acc[nt] = __builtin_amdgcn_mfma_f32_16x16x32_bf16(a2[kt], b, acc[nt], 0, 0, 0);
            }
    }
    int rbase = m0 + lq * 4;
    int cn[4];
    #pragma unroll
    for (int r = 0; r < 4; r++) cn[r] = cnb[rbase + r];
    #pragma unroll
    for (int nt = 0; nt < 8; nt++) {
        int col = nt * 16 + lm;
        float bs = b3[col];
        float mu2 = sum2[col] * INV_NT;
        float var2 = sq2[col] * INV_NT - mu2 * mu2;
        float sc2 = rsqrtf(var2 + 1e-5f) * g2[col];
        float sh2 = bb2[col] - mu2 * sc2;
        #pragma unroll
        for (int r = 0; r < 4; r++) {
            float v = acc[nt][r] + bs;
            v += b2f(T1[(lq * 4 + r) * TSTR + col]);
            v = fmaf(b2f(hgBb[(size_t)cn[r] * HH + col]), sc2, v + sh2);
            v = fmaxf(v, 0.f);
            T2[(lq * 4 + r) * TSTR + col] = f2b(v);
        }
    }
    __syncthreads();
    #pragma unroll
    for (int i = 0; i < 4; i++) {
        int idx = i * 64 + lane;
        int row = idx >> 4, ch = idx & 15;
        bf16x8 v = *(const bf16x8*)&T2[row * TSTR + ch * 8];
        *(bf16x8*)(xb + (size_t)(m0 + row) * HH + ch * 8) = v;
    }
    if (!w1n) return;
    __syncthreads();

    bf16x8 a3[4];
    #pragma unroll
    for (int kt = 0; kt < 4; kt++)
        a3[kt] = *(const bf16x8*)&T2[lm * TSTR + kt * 32 + lq * 8];
    f32x4 acc3[4];
    #pragma unroll
    for (int i = 0; i < 4; i++) acc3[i] = (f32x4){0.f, 0.f, 0.f, 0.f};
    {
        const ushort* Bp = w1n + (size_t)lane * 8;
        #pragma unroll
        for (int nt = 0; nt < 4; nt++)
            #pragma unroll
            for (int kt = 0; kt < 4; kt++) {
                bf16x8 b = *(const bf16x8*)(Bp + ((size_t)(nt * 4 + kt)) * 512);
                acc3[nt] = __builtin_amdgcn_mfma_f32_16x16x32_bf16(a3[kt], b, acc3[nt], 0, 0, 0);
            }
    }
    #pragma unroll
    for (int nt = 0; nt < 4; nt++) {
        int col = nt * 16 + lm;
        #pragma unroll
        for (int r = 0; r < 4; r++)
            T1[(lq * 4 + r) * TSTR + col] = f2b(acc3[nt][r]);
    }
    __syncthreads();
    #pragma unroll
    for (int i = 0; i < 2; i++) {
        int idx = i * 64 + lane;
        int row = idx >> 3, ch = idx & 7;
        bf16x8 v = *(const bf16x8*)&T1[row * TSTR + ch * 8];
        *(bf16x8*)(h1b + (size_t)(m0 + row) * FF + ch * 8) = v;
    }
}

// ---------------- output head with fused two-level max pool ----------------
__global__ __launch_bounds__(128) void out_layer_kernel(
    const ushort* __restrict__ xb, const float* __restrict__ w1,
    const float* __restrict__ b1, const float* __restrict__ w2,
    const float* __restrict__ b2, float* __restrict__ out)
{
    int m = blockIdx.x, f = threadIdx.x;
    const ushort* base = xb + (size_t)m * 256 * HH + f;
    float mx = -3.4e38f;
    for (int r = 0; r < 256; r++)
        mx = fmaxf(mx, b2f(base[(size_t)r * HH]));
    __shared__ float xs[128];
    xs[f] = mx;
    __syncthreads();
    float acc = b1[f];
    for (int k = 0; k < 128; k++) acc = fmaf(xs[k], w1[k * HH + f], acc);
    acc = fmaxf(acc, 0.f) * w2[f];
    __shared__ float red[128];
    red[f] = acc;
    __syncthreads();
    for (int off = 64; off > 0; off >>= 1) {
        if (f < off) red[f] += red[f + off];
        __syncthreads();
    }
    if (f == 0) out[m] = red[0] + b2[0];
}

extern "C" void kernel_launch(void* const* d_in, const int* in_sizes, int n_in,
                              void* d_out, int out_size, void* d_ws, size_t ws_size,
                              hipStream_t stream)
{
    const int*   x_topo    = (const int*)d_in[0];
    const float* pos       = (const float*)d_in[1];
    const int*   eic       = (const int*)d_in[2];
    const int*   eig       = (const int*)d_in[3];
    const int*   eattr     = (const int*)d_in[4];
    const int*   cnb       = (const int*)d_in[5];
    const float* atom_emb  = (const float*)d_in[8];
    const float* cf_lin1_w = (const float*)d_in[9];
    const float* cf_mlp_w1 = (const float*)d_in[10];
    const float* cf_mlp_b1 = (const float*)d_in[11];
    const float* cf_mlp_w2 = (const float*)d_in[12];
    const float* cf_mlp_b2 = (const float*)d_in[13];
    const float* cf_lin2_w = (const float*)d_in[14];
    const float* cf_lin2_b = (const float*)d_in[15];
    const float* lin_w     = (const float*)d_in[16];
    const float* lin_b     = (const float*)d_in[17];
    const float* bond_emb  = (const float*)d_in[18];
    const float* gin_w1    = (const float*)d_in[19];
    const float* gin_b1    = (const float*)d_in[20];
    const float* gin_w2    = (const float*)d_in[21];
    const float* gin_b2    = (const float*)d_in[22];
    const float* gin_bn_g  = (const float*)d_in[23];
    const float* gin_bn_b  = (const float*)d_in[24];
    const float* bn_g      = (const float*)d_in[25];
    const float* bn_b      = (const float*)d_in[26];
    const float* gin_eps   = (const float*)d_in[27];
    const float* out_w1    = (const float*)d_in[28];
    const float* out_b1    = (const float*)d_in[29];
    const float* out_w2    = (const float*)d_in[30];
    const float* out_b2    = (const float*)d_in[31];
    float* out = (float*)d_out;

    char* wsb = (char*)d_ws;
    size_t off = 0;
    auto alloc = [&](size_t nbytes) -> void* {
        void* p = (void*)(wsb + off);
        off += (nbytes + 255) & ~(size_t)255;
        return p;
    };
    ushort* xb      = (ushort*)alloc((size_t)NN * HH * 2);
    ushort* h1b     = (ushort*)alloc((size_t)NN * FF * 2);
    ushort* aggb    = (ushort*)alloc((size_t)NN * FF * 2);
    ushort* xaggb   = (ushort*)alloc((size_t)NT * HH * 2);
    ushort* hgA     = (ushort*)alloc((size_t)NT * HH * 2);
    ushort* hgB     = (ushort*)alloc((size_t)NT * HH * 2);
    float*  table_all  = (float*)alloc((size_t)4 * TBL * 64 * 4);
    ushort2* table2_all = (ushort2*)alloc((size_t)4 * TBL * 64 * 4);
    // stats + cntA + degC + ovf_cnt adjacent -> single memset
    float*  stats   = (float*)alloc((size_t)4 * 4 * 128 * 4);     // 8 KB
    int*    cntA    = (int*)alloc((size_t)NN * 4);                // 256 KB
    int*    degC    = (int*)alloc((size_t)NT * 4);                // 32 KB
    int*    ovf_cnt = (int*)alloc(256);                           // 256 B
    int*    offsC   = (int*)alloc((NT + 1) * 4);
    int*    curC    = (int*)alloc(NT * 4);
    int*    pay_pad = (int*)alloc((size_t)NN * CAP * 4);          // 8 MB padded CSR
    int2*   ovf     = (int2*)alloc((size_t)OVF_CAP * 8);
    int2*   gpay    = (int2*)alloc((size_t)EG * 8);
    ushort* w1f     = (ushort*)alloc((size_t)4 * HH * FF * 2);
    ushort* w2f     = (ushort*)alloc((size_t)4 * FF * HH * 2);
    ushort* wlf     = (ushort*)alloc((size_t)4 * HH * HH * 2);
    ushort* gw1f    = (ushort*)alloc((size_t)4 * HH * HH * 2);
    ushort* gw2f    = (ushort*)alloc((size_t)4 * HH * HH * 2);

    // --- single memset covering stats + cntA + degC + ovf_cnt (adjacent, 256B-aligned) ---
    hipMemsetAsync(stats, 0,
        ((size_t)4 * 4 * 128 * 4 + 255 & ~(size_t)255) +
        ((size_t)NN * 4 + 255 & ~(size_t)255) +
        ((size_t)NT * 4 + 255 & ~(size_t)255) + 256, stream);
    // --- sentinel fill of padded CSR (must complete before setup's fused scatter) ---
    hipMemsetD32Async((hipDeviceptr_t)pay_pad, SENT, (size_t)NN * CAP, stream);

    // --- mega setup: scatter(4 edges/thread) + ghist + embed + Wf-table + weight prep ---
    setup_kernel<<<SETUP_B4, 256, 0, stream>>>(
        eic, cnb, eig, pos, atom_emb, x_topo, degC, xb, cntA, pay_pad, ovf_cnt, ovf,
        cf_mlp_w1, cf_mlp_b1, cf_mlp_w2, cf_mlp_b2, table_all,
        cf_lin1_w, cf_lin2_w, lin_w, gin_w1, gin_w2, w1f, w2f, wlf, gw1f, gw2f);
    scanC_kernel<<<1, 256, 0, stream>>>(degC, offsC, curC);
    scatter_graph_kernel<<<EG / 256, 256, 0, stream>>>(eig, eattr, curC, gpay);
    pack_table_kernel<<<4 * TBL * 64 / 256, 256, 0, stream>>>(table_all, table2_all);

    // initial h1b = xb @ cf_lin1_w[0]
    gemm_bf16_kernel<<<NN / 64, 256, 0, stream>>>(xb, w1f, h1b);

    for (int l = 0; l < 4; l++) {
        const ushort2* table2 = table2_all + (size_t)l * TBL * 64;
        float* sum1 = stats + (size_t)l * 512;
        float* sq1  = sum1 + 128;
        float* sum2 = sum1 + 256;
        float* sq2  = sum1 + 384;
        edge_xagg_kernel<<<NEB + NT * HH / 256, 256, 0, stream>>>(
            cntA, pay_pad, ovf_cnt, ovf, table2, h1b, aggb, xb, xaggb);
        gin_gemm1_kernel<<<NT / 64, 256, 0, stream>>>(
            offsC, gpay, xaggb, bond_emb + (size_t)l * 10 * HH, gin_eps + l,
            gw1f + (size_t)l * HH * HH, gin_b1 + (size_t)l * HH, hgA, sum1, sq1);
        gemm_bn_stats_kernel<<<NT / 64, 256, 0, stream>>>(
            hgA, sum1, sq1, gin_bn_g + (size_t)l * HH, gin_bn_b + (size_t)l * HH,
            gw2f + (size_t)l * HH * HH, gin_b2 + (size_t)l * HH, hgB, sum2, sq2);
        fused_lin_kernel<<<NN / 64, 256, 0, stream>>>(
            aggb, w2f + (size_t)l * FF * HH, cf_lin2_b + (size_t)l * HH,
            wlf + (size_t)l * HH * HH, lin_b + (size_t)l * HH,
            hgB, sum2, sq2, bn_g + (size_t)l * HH, bn_b + (size_t)l * HH,
            cnb, (l < 3) ? (w1f + (size_t)(l + 1) * HH * FF) : nullptr,
            xb, h1b);
    }

    out_layer_kernel<<<MM, 128, 0, stream>>>(xb, out_w1, out_b1, out_w2, out_b2, out);
}

// Round 7
// 589.133 us; speedup vs baseline: 1.0850x; 1.0813x over previous
//
#include <hip/hip_runtime.h>
#include <hip/hip_bf16.h>

#define EC 1048576   // conformer edges
#define NN 65536     // conformer nodes
#define NT 8192      // topo nodes
#define MM 256
#define HH 128
#define FF 64
#define GG 50
#define EG 32768     // graph edges

#define TBL 2048            // Wf table entries per layer (512KB/layer -> L2-resident)
#define TBL_SHIFT 11
#define TRANGE 14.0f

#define CAP 32              // padded-CSR slots per conformer node (Poisson(16))
#define OVF_CAP 8192        // conformer overflow list capacity
#define GCAP 32             // padded-CSR slots per topo node (Poisson(4))
#define GOVF_CAP 1024       // graph overflow list capacity
#define NEB (NN * 64 / 256)     // edge-agg blocks in merged dispatch

// sentinel pay: table index 2047 (never produced by real edges: i0<=2046), fr=0, row=0
// table2[2047] is forced to {0,0} -> contribution exactly 0 without any masking
#define SENT 0xFFE00000

constexpr float STEP = 10.0f / 49.0f;
constexpr float GC = -0.5f / (STEP * STEP);

typedef __attribute__((ext_vector_type(8))) short bf16x8;
typedef __attribute__((ext_vector_type(4))) float f32x4;

__device__ __forceinline__ ushort f2b(float v) {
    __hip_bfloat16 h = __float2bfloat16(v);
    return *(ushort*)&h;
}
__device__ __forceinline__ float b2f(ushort u) {
    return __uint_as_float(((unsigned)u) << 16);
}

// ---------------- weight prep helper ----------------
__device__ __forceinline__ void prep_one(
    const float* __restrict__ W, ushort* __restrict__ Wf, int K, int N, int idx)
{
    int sz = K * N;
    int l = idx / sz;
    int t = idx - l * sz;
    int j = t & 7;
    int lane = (t >> 3) & 63;
    int rest = t >> 9;
    int KTl = K >> 5;
    int kt = rest % KTl;
    int nt = rest / KTl;
    int k = kt * 32 + (lane >> 4) * 8 + j;
    int n = nt * 16 + (lane & 15);
    Wf[idx] = f2b(W[(size_t)l * sz + (size_t)k * N + n]);
}

// ---------------- mega setup: conf scatter + graph scatter + embed + Wf-table + prep --------
// Conformer scatter: 1 edge/thread (measured-best; far-atomic rate is the floor).
// Graph scatter: padded-CSR via same slot trick (replaces scanC+scatter_graph dispatches).
// pay_pad sentinel-filled + cntA/gcnt/ovf_cnt zeroed BEFORE this kernel.
#define SETUP_B0 (EC / 256)
#define SETUP_B1 (SETUP_B0 + EG / 256)
#define SETUP_B2 (SETUP_B1 + NN * HH / 8 / 256)
#define SETUP_B3 (SETUP_B2 + 4 * TBL / 4)
#define SETUP_B4 (SETUP_B3 + 1024)
__global__ __launch_bounds__(256) void setup_kernel(
    const int* __restrict__ eic, const int* __restrict__ cnb,
    const int* __restrict__ eig, const int* __restrict__ eattr,
    const float* __restrict__ pos,
    const float* __restrict__ emb, const int* __restrict__ xtopo,
    ushort* __restrict__ xb,
    int* __restrict__ cntA, int* __restrict__ pay_pad,
    int* __restrict__ ovf_cnt, int2* __restrict__ ovf,
    int* __restrict__ gcnt, int2* __restrict__ gpay_pad, int4* __restrict__ govf,
    const float* __restrict__ mw1, const float* __restrict__ mb1,
    const float* __restrict__ mw2, const float* __restrict__ mb2,
    float* __restrict__ table_all,
    const float* __restrict__ cf_lin1_w, const float* __restrict__ cf_lin2_w,
    const float* __restrict__ lin_w, const float* __restrict__ gin_w1,
    const float* __restrict__ gin_w2,
    ushort* __restrict__ w1f, ushort* __restrict__ w2f, ushort* __restrict__ wlf,
    ushort* __restrict__ gw1f, ushort* __restrict__ gw2f)
{
    int b = blockIdx.x, tid = threadIdx.x;
    if (b < SETUP_B0) {
        // conformer edge: distance + direct padded-CSR scatter (1 edge/thread)
        int e = b * 256 + tid;
        int r = eic[e], c = eic[EC + e];
        float dx = pos[r*3+0] - pos[c*3+0];
        float dy = pos[r*3+1] - pos[c*3+1];
        float dz = pos[r*3+2] - pos[c*3+2];
        float w = sqrtf(dx*dx + dy*dy + dz*dz + 1e-12f);
        float u = fminf(w * ((TBL - 1) / TRANGE), 2046.96875f);
        int pay = (((int)(u * 32.0f)) << 16) | (r & 0xFFFF);   // 11.5 fixed point | row
        int slot = atomicAdd(&cntA[c], 1);
        if (slot < CAP) {
            pay_pad[c * CAP + slot] = pay;
        } else {
            int o = atomicAdd(&ovf_cnt[0], 1);
            if (o < OVF_CAP) ovf[o] = make_int2(c, pay);   // hard bound
        }
    } else if (b < SETUP_B1) {
        // graph edge: padded-CSR scatter (replaces histogram+scan+scatter pipeline)
        int e = (b - SETUP_B0) * 256 + tid;
        int src = eig[e], dst = eig[EG + e];
        int at = eattr[e];
        int slot = atomicAdd(&gcnt[dst], 1);
        if (slot < GCAP) {
            gpay_pad[dst * GCAP + slot] = make_int2(src, at);
        } else {
            int o = atomicAdd(&ovf_cnt[1], 1);
            if (o < GOVF_CAP) govf[o] = make_int4(dst, src, at, 0);   // hard bound
        }
    } else if (b < SETUP_B2) {
        // vectorized embedding broadcast: 8 features per thread
        int idx = (b - SETUP_B1) * 256 + tid;   // 0 .. NN*HH/8
        int n = idx >> 4;
        int f8 = (idx & 15) << 3;
        const float* e = emb + (size_t)xtopo[cnb[n]] * HH + f8;
        float4 v0 = *(const float4*)e;
        float4 v1 = *(const float4*)(e + 4);
        ushort u[8] = {f2b(v0.x), f2b(v0.y), f2b(v0.z), f2b(v0.w),
                       f2b(v1.x), f2b(v1.y), f2b(v1.z), f2b(v1.w)};
        *(bf16x8*)(xb + ((size_t)idx << 3)) = *(const bf16x8*)u;
    } else if (b < SETUP_B3) {
        // Wf table: 4 entries per block, one per wave
        int entry = (b - SETUP_B2) * 4 + (tid >> 6);
        int l = entry >> TBL_SHIFT;
        int p = entry & (TBL - 1);
        int lane = tid & 63;
        int wv = tid >> 6;
        const float* w1 = mw1 + (size_t)l * GG * FF;
        const float* b1 = mb1 + (size_t)l * FF;
        const float* w2 = mw2 + (size_t)l * FF * FF;
        const float* b2 = mb2 + (size_t)l * FF;
        float w = p * (TRANGE / (TBL - 1));
        float t = b1[lane];
        for (int g = 0; g < GG; g++) {
            float d = w - g * STEP;
            float ea = __expf(GC * d * d);
            t = fmaf(ea, w1[g * 64 + lane], t);
        }
        __shared__ float ts[4][64];
        ts[wv][lane] = fmaxf(t, 0.f);
        __syncthreads();
        float wf = b2[lane];
        for (int i = 0; i < 64; i++)
            wf = fmaf(ts[wv][i], w2[i * 64 + lane], wf);
        float cw = 0.5f * (__cosf(w * (3.14159265358979323846f / 10.0f)) + 1.0f);
        table_all[((size_t)l * TBL + p) * 64 + lane] = wf * cw;
    } else {
        int pb = b - SETUP_B3;
        if (pb < 128)       prep_one(cf_lin1_w, w1f, HH, FF, pb * 256 + tid);
        else if (pb < 256)  prep_one(cf_lin2_w, w2f, FF, HH, (pb - 128) * 256 + tid);
        else if (pb < 512)  prep_one(lin_w, wlf, HH, HH, (pb - 256) * 256 + tid);
        else if (pb < 768)  prep_one(gin_w1, gw1f, HH, HH, (pb - 512) * 256 + tid);
        else                prep_one(gin_w2, gw2f, HH, HH, (pb - 768) * 256 + tid);
    }
}

// ---------------- stage2: pack table (bf16 pair) + initial h1b GEMM, one dispatch ----------------
#define S2_B0 (4 * TBL * 64 / 256)      // 2048 pack blocks
#define S2_B1 (S2_B0 + NN / 64)         // + 1024 gemm blocks
__global__ __launch_bounds__(256) void stage2_kernel(
    const float* __restrict__ table_all, ushort2* __restrict__ table2_all,
    const ushort* __restrict__ A, const ushort* __restrict__ Bf,
    ushort* __restrict__ Cb)
{
    int b = blockIdx.x, tid = threadIdx.x;
    if (b < S2_B0) {
        int idx = b * 256 + tid;   // 4*TBL*64
        int f = idx & 63;
        int rest = idx >> 6;
        int i = rest & (TBL - 1);
        int l = rest >> TBL_SHIFT;
        if (i == TBL - 1) {
            table2_all[idx] = make_ushort2(0, 0);   // sentinel target {0,0}
            return;
        }
        const float* T = table_all + ((size_t)l * TBL) * 64;
        float t0 = T[(size_t)i * 64 + f];
        float t1 = T[(size_t)(i + 1) * 64 + f];
        // dt prescaled by 1/32 (exact pow2 shift in bf16): wf = fmaf(dts, (float)frac5, t0)
        table2_all[idx] = make_ushort2(f2b(t0), f2b((t1 - t0) * 0.03125f));
    } else {
        // initial h1b = xb @ cf_lin1_w[0], N=64 K=128
        int wave = tid >> 6, lane = tid & 63;
        int m0 = ((b - S2_B0) * 4 + wave) * 16;
        int arow = m0 + (lane & 15);
        int ak = (lane >> 4) * 8;
        bf16x8 a[4];
        const ushort* Ap = A + (size_t)arow * 128 + ak;
        #pragma unroll
        for (int kt = 0; kt < 4; kt++)
            a[kt] = *(const bf16x8*)(Ap + kt * 32);
        f32x4 acc[4];
        #pragma unroll
        for (int i = 0; i < 4; i++) acc[i] = (f32x4){0.f, 0.f, 0.f, 0.f};
        const ushort* Bp = Bf + (size_t)lane * 8;
        #pragma unroll
        for (int nt = 0; nt < 4; nt++)
            #pragma unroll
            for (int kt = 0; kt < 4; kt++) {
                bf16x8 bb = *(const bf16x8*)(Bp + ((size_t)(nt * 4 + kt)) * 512);
                acc[nt] = __builtin_amdgcn_mfma_f32_16x16x32_bf16(a[kt], bb, acc[nt], 0, 0, 0);
            }
        int col0 = lane & 15;
        int rbase = m0 + (lane >> 4) * 4;
        #pragma unroll
        for (int nt = 0; nt < 4; nt++) {
            int col = nt * 16 + col0;
            #pragma unroll
            for (int r = 0; r < 4; r++)
                Cb[(size_t)(rbase + r) * 64 + col] = f2b(acc[nt][r]);
        }
    }
}

// 8-wide edge batch, NO masking (sentinel pays -> exact 0 contribution).
// pp is wave-uniform; pays forced to SGPR via readfirstlane so all the
// unpack/address math runs on the SALU pipe; gathers are saddr+voffset32.
#define EDGE8(BASE) { \
    int pq[8]; \
    { int4 q0 = *(const int4*)(pp + BASE); \
      int4 q1 = *(const int4*)(pp + BASE + 4); \
      pq[0]=__builtin_amdgcn_readfirstlane(q0.x); \
      pq[1]=__builtin_amdgcn_readfirstlane(q0.y); \
      pq[2]=__builtin_amdgcn_readfirstlane(q0.z); \
      pq[3]=__builtin_amdgcn_readfirstlane(q0.w); \
      pq[4]=__builtin_amdgcn_readfirstlane(q1.x); \
      pq[5]=__builtin_amdgcn_readfirstlane(q1.y); \
      pq[6]=__builtin_amdgcn_readfirstlane(q1.z); \
      pq[7]=__builtin_amdgcn_readfirstlane(q1.w); } \
    float h[8]; \
    _Pragma("unroll") \
    for (int q = 0; q < 8; q++) \
        h[q] = b2f(*(const ushort*)(h1c + ((((unsigned)(pq[q] & 0xFFFF)) << 7) + lane2))); \
    unsigned tt[8]; \
    _Pragma("unroll") \
    for (int q = 0; q < 8; q++) \
        tt[q] = *(const unsigned*)(tbc + (((((unsigned)pq[q]) >> 21) << 8) + lane4)); \
    _Pragma("unroll") \
    for (int q = 0; q < 8; q++) { \
        float fr = (float)((unsigned)((pq[q] >> 16) & 31)); \
        float t0 = __uint_as_float(tt[q] << 16); \
        float dts = __uint_as_float(tt[q] & 0xFFFF0000u); \
        float wf = fmaf(dts, fr, t0); \
        if (q & 1) acc1 = fmaf(h[q], wf, acc1); else acc0 = fmaf(h[q], wf, acc0); \
    } }

// ---------------- merged: padded-CSR edge aggregation + closed-form xagg max ----------------
__global__ __launch_bounds__(256) void edge_xagg_kernel(
    const int* __restrict__ cntA, const int* __restrict__ pay_pad,
    const int* __restrict__ ovf_cnt, const int2* __restrict__ ovf,
    const ushort2* __restrict__ table2, const ushort* __restrict__ h1b,
    ushort* __restrict__ aggb,
    const ushort* __restrict__ xb, ushort* __restrict__ xaggb)
{
    int tid = threadIdx.x;
    if (blockIdx.x < NEB) {
        int lane = tid & 63;
        int node = __builtin_amdgcn_readfirstlane((blockIdx.x * 256 + tid) >> 6);
        unsigned lane2 = (unsigned)lane * 2;
        unsigned lane4 = (unsigned)lane * 4;
        const char* h1c = (const char*)h1b;
        const char* tbc = (const char*)table2;
        int deg = cntA[node];
        int n1 = min(deg, CAP);
        const int* pp = pay_pad + (size_t)node * CAP;
        float acc0 = 0.f, acc1 = 0.f;
        EDGE8(0);
        if (n1 > 8) {
            EDGE8(8);
            if (n1 > 16) {
                EDGE8(16);
                if (n1 > 24) EDGE8(24);
            }
        }
        float acc = acc0 + acc1;
        if (deg > CAP) {   // rare overflow path (Poisson(16) tail): scan tiny list
            int no = min(ovf_cnt[0], OVF_CAP);   // hard bound
            for (int j = 0; j < no; j++) {
                int2 o = ovf[j];
                if (o.x == node) {
                    unsigned uf = (unsigned)o.y >> 16;
                    int i0 = uf >> 5;
                    float fr = (float)(uf & 31);
                    ushort2 ttv = table2[(size_t)i0 * 64 + lane];
                    acc = fmaf(b2f(h1b[(size_t)(o.y & 0xFFFF) * 64 + lane]),
                               fmaf(b2f(ttv.y), fr, b2f(ttv.x)), acc);
                }
            }
        }
        aggb[(size_t)node * 64 + lane] = f2b(acc);
    } else {
        int idx = (blockIdx.x - NEB) * 256 + tid;   // NT*HH
        int tn = idx >> 7, f = idx & 127;
        int m = tn >> 5, a = tn & 31;
        const ushort* base = xb + ((size_t)((m << 8) + a)) * HH + f;
        float mx = -3.4e38f;
        #pragma unroll
        for (int k = 0; k < 8; k++)
            mx = fmaxf(mx, b2f(base[(size_t)(k << 5) * HH]));
        xaggb[idx] = f2b(mx);
    }
}

#define TSTR 136

// ---------------- GIN GEMM1 with fused magg/hg0 tile build + stats (bf16 hgA out) ----------------
// graph neighbors now read from padded CSR (gcnt/gpay_pad/govf) built in setup.
__global__ __launch_bounds__(256) void gin_gemm1_kernel(
    const int* __restrict__ gcnt, const int2* __restrict__ gpay_pad,
    const int* __restrict__ ovf_cnt, const int4* __restrict__ govf,
    const ushort* __restrict__ xaggb, const float* __restrict__ bemb,
    const float* __restrict__ eps, const ushort* __restrict__ Bf,
    const float* __restrict__ bias, ushort* __restrict__ Cb,
    float* __restrict__ gsum, float* __restrict__ gsq)
{
    __shared__ ushort hg0s[64 * TSTR];
    __shared__ float ssum[128], ssq[128];
    int tid = threadIdx.x;
    if (tid < 128) { ssum[tid] = 0.f; ssq[tid] = 0.f; }
    {
        int row = tid >> 2;
        int fc = (tid & 3) * 32;
        int tn = blockIdx.x * 64 + row;
        float e1 = 1.0f + eps[0];
        float acc[32];
        const ushort* xo = xaggb + (size_t)tn * HH + fc;
        #pragma unroll
        for (int c = 0; c < 4; c++) {
            bf16x8 x = *(const bf16x8*)(xo + c * 8);
            #pragma unroll
            for (int j = 0; j < 8; j++)
                acc[c * 8 + j] = e1 * b2f((ushort)x[j]);
        }
        int deg = gcnt[tn];
        int gn = min(deg, GCAP);
        const int2* gp = gpay_pad + (size_t)tn * GCAP;
        for (int p = 0; p < gn; p++) {
            int2 g = gp[p];
            const ushort* xs = xaggb + (size_t)g.x * HH + fc;
            const float* bs = bemb + (size_t)g.y * HH + fc;
            #pragma unroll
            for (int c = 0; c < 4; c++) {
                bf16x8 x = *(const bf16x8*)(xs + c * 8);
                float4 b0 = *(const float4*)(bs + c * 8);
                float4 b1 = *(const float4*)(bs + c * 8 + 4);
                float bb[8] = {b0.x, b0.y, b0.z, b0.w, b1.x, b1.y, b1.z, b1.w};
                #pragma unroll
                for (int j = 0; j < 8; j++)
                    acc[c * 8 + j] += fmaxf(b2f((ushort)x[j]) + bb[j], 0.f);
            }
        }
        if (deg > GCAP) {   // rare overflow path
            int no = min(ovf_cnt[1], GOVF_CAP);
            for (int j2 = 0; j2 < no; j2++) {
                int4 o = govf[j2];
                if (o.x == tn) {
                    const ushort* xs = xaggb + (size_t)o.y * HH + fc;
                    const float* bs = bemb + (size_t)o.z * HH + fc;
                    #pragma unroll
                    for (int c = 0; c < 4; c++) {
                        bf16x8 x = *(const bf16x8*)(xs + c * 8);
                        float4 b0 = *(const float4*)(bs + c * 8);
                        float4 b1 = *(const float4*)(bs + c * 8 + 4);
                        float bb[8] = {b0.x, b0.y, b0.z, b0.w, b1.x, b1.y, b1.z, b1.w};
                        #pragma unroll
                        for (int j = 0; j < 8; j++)
                            acc[c * 8 + j] += fmaxf(b2f((ushort)x[j]) + bb[j], 0.f);
                    }
                }
            }
        }
        ushort* dst = hg0s + row * TSTR + fc;
        #pragma unroll
        for (int j = 0; j < 32; j++) dst[j] = f2b(acc[j]);
    }
    __syncthreads();
    int wave = tid >> 6, lane = tid & 63;
    int lm = lane & 15, lq = lane >> 4;
    int ak = lq * 8;
    bf16x8 a[4];
    #pragma unroll
    for (int kt = 0; kt < 4; kt++)
        a[kt] = *(const bf16x8*)&hg0s[(wave * 16 + lm) * TSTR + ak + kt * 32];
    f32x4 acc[8];
    #pragma unroll
    for (int i = 0; i < 8; i++) acc[i] = (f32x4){0.f, 0.f, 0.f, 0.f};
    const ushort* Bp = Bf + (size_t)lane * 8;
    #pragma unroll
    for (int nt = 0; nt < 8; nt++)
        #pragma unroll
        for (int kt = 0; kt < 4; kt++) {
            bf16x8 b = *(const bf16x8*)(Bp + ((size_t)(nt * 4 + kt)) * 512);
            acc[nt] = __builtin_amdgcn_mfma_f32_16x16x32_bf16(a[kt], b, acc[nt], 0, 0, 0);
        }
    int rbase = blockIdx.x * 64 + wave * 16 + lq * 4;
    #pragma unroll
    for (int nt = 0; nt < 8; nt++) {
        int col = nt * 16 + lm;
        float bs = bias[col];
        float ps = 0.f, pq = 0.f;
        #pragma unroll
        for (int r = 0; r < 4; r++) {
            float v = acc[nt][r] + bs;
            Cb[(size_t)(rbase + r) * 128 + col] = f2b(v);
            ps += v; pq += v * v;
        }
        atomicAdd(&ssum[col], ps);
        atomicAdd(&ssq[col], pq);
    }
    __syncthreads();
    if (tid < 128) {
        atomicAdd(&gsum[tid], ssum[tid]);
        atomicAdd(&gsq[tid], ssq[tid]);
    }
}

// ---------------- GIN gemm 2: A = relu(BN1(hgA bf16)); hgB(bf16) = A@B + bias, + stats ----------------
__global__ __launch_bounds__(256) void gemm_bn_stats_kernel(
    const ushort* __restrict__ Araw, const float* __restrict__ sum1,
    const float* __restrict__ sq1, const float* __restrict__ g1,
    const float* __restrict__ bb1, const ushort* __restrict__ Bf,
    const float* __restrict__ bias, ushort* __restrict__ Cb,
    float* __restrict__ gsum, float* __restrict__ gsq)
{
    __shared__ float ssum[128], ssq[128];
    int tid = threadIdx.x;
    if (tid < 128) { ssum[tid] = 0.f; ssq[tid] = 0.f; }
    __syncthreads();
    int wave = tid >> 6, lane = tid & 63;
    int m0 = (blockIdx.x * 4 + wave) * 16;
    int arow = m0 + (lane & 15);
    int ak = (lane >> 4) * 8;
    const float INV_NT = 1.0f / NT;
    bf16x8 a[4];
    const ushort* Ap = Araw + (size_t)arow * 128 + ak;
    #pragma unroll
    for (int kt = 0; kt < 4; kt++) {
        bf16x8 raw = *(const bf16x8*)(Ap + kt * 32);
        ushort ub[8];
        #pragma unroll
        for (int j = 0; j < 8; j++) {
            int k = ak + kt * 32 + j;
            float mu = sum1[k] * INV_NT;
            float var = sq1[k] * INV_NT - mu * mu;
            float inv = rsqrtf(var + 1e-5f);
            float w = fmaxf((b2f((ushort)raw[j]) - mu) * inv * g1[k] + bb1[k], 0.f);
            ub[j] = f2b(w);
        }
        a[kt] = *(bf16x8*)ub;
    }
    f32x4 acc[8];
    #pragma unroll
    for (int i = 0; i < 8; i++) acc[i] = (f32x4){0.f, 0.f, 0.f, 0.f};
    const ushort* Bp = Bf + (size_t)lane * 8;
    #pragma unroll
    for (int nt = 0; nt < 8; nt++)
        #pragma unroll
        for (int kt = 0; kt < 4; kt++) {
            bf16x8 b = *(const bf16x8*)(Bp + ((size_t)(nt * 4 + kt)) * 512);
            acc[nt] = __builtin_amdgcn_mfma_f32_16x16x32_bf16(a[kt], b, acc[nt], 0, 0, 0);
        }
    int col0 = lane & 15;
    int rbase = m0 + (lane >> 4) * 4;
    #pragma unroll
    for (int nt = 0; nt < 8; nt++) {
        int col = nt * 16 + col0;
        float bs = bias[col];
        float ps = 0.f, pq = 0.f;
        #pragma unroll
        for (int r = 0; r < 4; r++) {
            float v = acc[nt][r] + bs;
            Cb[(size_t)(rbase + r) * 128 + col] = f2b(v);
            ps += v; pq += v * v;
        }
        atomicAdd(&ssum[col], ps);
        atomicAdd(&ssq[col], pq);
    }
    __syncthreads();
    if (tid < 128) {
        atomicAdd(&gsum[tid], ssum[tid]);
        atomicAdd(&gsq[tid], ssq[tid]);
    }
}

// ---------------- fused CFConv tail: 3 chained GEMMs, coalesced epilogues ----------------
__global__ __launch_bounds__(256) void fused_lin_kernel(
    const ushort* __restrict__ aggb, const ushort* __restrict__ w2,
    const float* __restrict__ b2, const ushort* __restrict__ w3,
    const float* __restrict__ b3, const ushort* __restrict__ hgBb,
    const float* __restrict__ sum2, const float* __restrict__ sq2,
    const float* __restrict__ g2, const float* __restrict__ bb2,
    const int* __restrict__ cnb, const ushort* __restrict__ w1n,
    ushort* __restrict__ xb, ushort* __restrict__ h1b)
{
    __shared__ ushort t1s[4][16 * TSTR];
    __shared__ ushort t2s[4][16 * TSTR];
    int tid = threadIdx.x;
    int wave = tid >> 6, lane = tid & 63;
    int m0 = (blockIdx.x * 4 + wave) * 16;
    int lm = lane & 15;
    int lq = lane >> 4;
    ushort* T1 = t1s[wave];
    ushort* T2 = t2s[wave];
    const float INV_NT = 1.0f / NT;

    const ushort* Ap = aggb + (size_t)(m0 + lm) * 64 + lq * 8;
    bf16x8 a1[2];
    a1[0] = *(const bf16x8*)(Ap);
    a1[1] = *(const bf16x8*)(Ap + 32);
    f32x4 acc[8];
    #pragma unroll
    for (int i = 0; i < 8; i++) acc[i] = (f32x4){0.f, 0.f, 0.f, 0.f};
    {
        const ushort* Bp = w2 + (size_t)lane * 8;
        #pragma unroll
        for (int nt = 0; nt < 8; nt++)
            #pragma unroll
            for (int kt = 0; kt < 2; kt++) {
                bf16x8 b = *(const bf16x8*)(Bp + ((size_t)(nt * 2 + kt)) * 512);
                acc[nt] = __builtin_amdgcn_mfma_f32_16x16x32_bf16(a1[kt], b, acc[nt], 0, 0, 0);
            }
    }
    #pragma unroll
    for (int nt = 0; nt < 8; nt++) {
        int col = nt * 16 + lm;
        float bs = b2[col];
        #pragma unroll
        for (int r = 0; r < 4; r++) {
            float v = fmaxf(acc[nt][r] + bs, 0.f);
            T1[(lq * 4 + r) * TSTR + col] = f2b(v);
        }
    }
    __syncthreads();

    bf16x8 a2[4];
    #pragma unroll
    for (int kt = 0; kt < 4; kt++)
        a2[kt] = *(const bf16x8*)&T1[lm * TSTR + kt * 32 + lq * 8];
    __syncthreads();
    #pragma unroll
    for (int i = 0; i < 4; i++) {
        int idx = i * 64 + lane;
        int row = idx >> 4, ch = idx & 15;
        bf16x8 v = *(const bf16x8*)(xb + (size_t)(m0 + row) * HH + ch * 8);
        *(bf16x8*)&T1[row * TSTR + ch * 8] = v;
    }
    #pragma unroll
    for (int i = 0; i < 8; i++) acc[i] = (f32x4){0.f, 0.f, 0.f, 0.f};
    {
        const ushort* Bp = w3 + (size_t)lane * 8;
        #pragma unroll
        for (int nt = 0; nt < 8; nt++)
            #pragma unroll
            for (int kt = 0; kt < 4; kt++) {
                bf16x8 b = *(const bf16x8*)(Bp + ((size_t)(nt * 4 + kt)) * 512);
                acc[nt] = __builtin_amdgcn_mfma_f32_16x16x32_bf16(a2[kt], b, acc[nt], 0, 0, 0);
            }
    }
    int rbase = m0 + lq * 4;
    int cn[4];
    #pragma unroll
    for (int r = 0; r < 4; r++) cn[r] = cnb[rbase + r];
    #pragma unroll
    for (int nt = 0; nt < 8; nt++) {
        int col = nt * 16 + lm;
        float bs = b3[col];
        float mu2 = sum2[col] * INV_NT;
        float var2 = sq2[col] * INV_NT - mu2 * mu2;
        float sc2 = rsqrtf(var2 + 1e-5f) * g2[col];
        float sh2 = bb2[col] - mu2 * sc2;
        #pragma unroll
        for (int r = 0; r < 4; r++) {
            float v = acc[nt][r] + bs;
            v += b2f(T1[(lq * 4 + r) * TSTR + col]);
            v = fmaf(b2f(hgBb[(size_t)cn[r] * HH + col]), sc2, v + sh2);
            v = fmaxf(v, 0.f);
            T2[(lq * 4 + r) * TSTR + col] = f2b(v);
        }
    }
    __syncthreads();
    #pragma unroll
    for (int i = 0; i < 4; i++) {
        int idx = i * 64 + lane;
        int row = idx >> 4, ch = idx & 15;
        bf16x8 v = *(const bf16x8*)&T2[row * TSTR + ch * 8];
        *(bf16x8*)(xb + (size_t)(m0 + row) * HH + ch * 8) = v;
    }
    if (!w1n) return;
    __syncthreads();

    bf16x8 a3[4];
    #pragma unroll
    for (int kt = 0; kt < 4; kt++)
        a3[kt] = *(const bf16x8*)&T2[lm * TSTR + kt * 32 + lq * 8];
    f32x4 acc3[4];
    #pragma unroll
    for (int i = 0; i < 4; i++) acc3[i] = (f32x4){0.f, 0.f, 0.f, 0.f};
    {
        const ushort* Bp = w1n + (size_t)lane * 8;
        #pragma unroll
        for (int nt = 0; nt < 4; nt++)
            #pragma unroll
            for (int kt = 0; kt < 4; kt++) {
                bf16x8 b = *(const bf16x8*)(Bp + ((size_t)(nt * 4 + kt)) * 512);
                acc3[nt] = __builtin_amdgcn_mfma_f32_16x16x32_bf16(a3[kt], b, acc3[nt], 0, 0, 0);
            }
    }
    #pragma unroll
    for (int nt = 0; nt < 4; nt++) {
        int col = nt * 16 + lm;
        #pragma unroll
        for (int r = 0; r < 4; r++)
            T1[(lq * 4 + r) * TSTR + col] = f2b(acc3[nt][r]);
    }
    __syncthreads();
    #pragma unroll
    for (int i = 0; i < 2; i++) {
        int idx = i * 64 + lane;
        int row = idx >> 3, ch = idx & 7;
        bf16x8 v = *(const bf16x8*)&T1[row * TSTR + ch * 8];
        *(bf16x8*)(h1b + (size_t)(m0 + row) * FF + ch * 8) = v;
    }
}

// ---------------- output head with fused two-level max pool ----------------
__global__ __launch_bounds__(128) void out_layer_kernel(
    const ushort* __restrict__ xb, const float* __restrict__ w1,
    const float* __restrict__ b1, const float* __restrict__ w2,
    const float* __restrict__ b2, float* __restrict__ out)
{
    int m = blockIdx.x, f = threadIdx.x;
    const ushort* base = xb + (size_t)m * 256 * HH + f;
    float mx = -3.4e38f;
    for (int r = 0; r < 256; r++)
        mx = fmaxf(mx, b2f(base[(size_t)r * HH]));
    __shared__ float xs[128];
    xs[f] = mx;
    __syncthreads();
    float acc = b1[f];
    for (int k = 0; k < 128; k++) acc = fmaf(xs[k], w1[k * HH + f], acc);
    acc = fmaxf(acc, 0.f) * w2[f];
    __shared__ float red[128];
    red[f] = acc;
    __syncthreads();
    for (int off = 64; off > 0; off >>= 1) {
        if (f < off) red[f] += red[f + off];
        __syncthreads();
    }
    if (f == 0) out[m] = red[0] + b2[0];
}

extern "C" void kernel_launch(void* const* d_in, const int* in_sizes, int n_in,
                              void* d_out, int out_size, void* d_ws, size_t ws_size,
                              hipStream_t stream)
{
    const int*   x_topo    = (const int*)d_in[0];
    const float* pos       = (const float*)d_in[1];
    const int*   eic       = (const int*)d_in[2];
    const int*   eig       = (const int*)d_in[3];
    const int*   eattr     = (const int*)d_in[4];
    const int*   cnb       = (const int*)d_in[5];
    const float* atom_emb  = (const float*)d_in[8];
    const float* cf_lin1_w = (const float*)d_in[9];
    const float* cf_mlp_w1 = (const float*)d_in[10];
    const float* cf_mlp_b1 = (const float*)d_in[11];
    const float* cf_mlp_w2 = (const float*)d_in[12];
    const float* cf_mlp_b2 = (const float*)d_in[13];
    const float* cf_lin2_w = (const float*)d_in[14];
    const float* cf_lin2_b = (const float*)d_in[15];
    const float* lin_w     = (const float*)d_in[16];
    const float* lin_b     = (const float*)d_in[17];
    const float* bond_emb  = (const float*)d_in[18];
    const float* gin_w1    = (const float*)d_in[19];
    const float* gin_b1    = (const float*)d_in[20];
    const float* gin_w2    = (const float*)d_in[21];
    const float* gin_b2    = (const float*)d_in[22];
    const float* gin_bn_g  = (const float*)d_in[23];
    const float* gin_bn_b  = (const float*)d_in[24];
    const float* bn_g      = (const float*)d_in[25];
    const float* bn_b      = (const float*)d_in[26];
    const float* gin_eps   = (const float*)d_in[27];
    const float* out_w1    = (const float*)d_in[28];
    const float* out_b1    = (const float*)d_in[29];
    const float* out_w2    = (const float*)d_in[30];
    const float* out_b2    = (const float*)d_in[31];
    float* out = (float*)d_out;

    char* wsb = (char*)d_ws;
    size_t off = 0;
    auto alloc = [&](size_t nbytes) -> void* {
        void* p = (void*)(wsb + off);
        off += (nbytes + 255) & ~(size_t)255;
        return p;
    };
    ushort* xb      = (ushort*)alloc((size_t)NN * HH * 2);
    ushort* h1b     = (ushort*)alloc((size_t)NN * FF * 2);
    ushort* aggb    = (ushort*)alloc((size_t)NN * FF * 2);
    ushort* xaggb   = (ushort*)alloc((size_t)NT * HH * 2);
    ushort* hgA     = (ushort*)alloc((size_t)NT * HH * 2);
    ushort* hgB     = (ushort*)alloc((size_t)NT * HH * 2);
    float*  table_all  = (float*)alloc((size_t)4 * TBL * 64 * 4);
    ushort2* table2_all = (ushort2*)alloc((size_t)4 * TBL * 64 * 4);
    // stats + cntA + gcnt + ovf_cnt adjacent -> single memset (ovf_cnt[0]=conf, [1]=graph)
    float*  stats   = (float*)alloc((size_t)4 * 4 * 128 * 4);     // 8 KB
    int*    cntA    = (int*)alloc((size_t)NN * 4);                // 256 KB
    int*    gcnt    = (int*)alloc((size_t)NT * 4);                // 32 KB
    int*    ovf_cnt = (int*)alloc(256);                           // 256 B
    int*    pay_pad = (int*)alloc((size_t)NN * CAP * 4);          // 8 MB padded CSR
    int2*   ovf     = (int2*)alloc((size_t)OVF_CAP * 8);
    int2*   gpay_pad = (int2*)alloc((size_t)NT * GCAP * 8);       // 2 MB padded graph CSR
    int4*   govf    = (int4*)alloc((size_t)GOVF_CAP * 16);
    ushort* w1f     = (ushort*)alloc((size_t)4 * HH * FF * 2);
    ushort* w2f     = (ushort*)alloc((size_t)4 * FF * HH * 2);
    ushort* wlf     = (ushort*)alloc((size_t)4 * HH * HH * 2);
    ushort* gw1f    = (ushort*)alloc((size_t)4 * HH * HH * 2);
    ushort* gw2f    = (ushort*)alloc((size_t)4 * HH * HH * 2);

    // --- single memset covering stats + cntA + gcnt + ovf_cnt (adjacent, 256B-aligned) ---
    hipMemsetAsync(stats, 0,
        ((size_t)4 * 4 * 128 * 4 + 255 & ~(size_t)255) +
        ((size_t)NN * 4 + 255 & ~(size_t)255) +
        ((size_t)NT * 4 + 255 & ~(size_t)255) + 256, stream);
    // --- sentinel fill of padded conformer CSR ---
    hipMemsetD32Async((hipDeviceptr_t)pay_pad, SENT, (size_t)NN * CAP, stream);

    // --- mega setup: conf scatter + graph scatter + embed + Wf-table + weight prep ---
    setup_kernel<<<SETUP_B4, 256, 0, stream>>>(
        eic, cnb, eig, eattr, pos, atom_emb, x_topo, xb,
        cntA, pay_pad, ovf_cnt, ovf, gcnt, gpay_pad, govf,
        cf_mlp_w1, cf_mlp_b1, cf_mlp_w2, cf_mlp_b2, table_all,
        cf_lin1_w, cf_lin2_w, lin_w, gin_w1, gin_w2, w1f, w2f, wlf, gw1f, gw2f);
    // --- stage2: pack table + initial h1b GEMM ---
    stage2_kernel<<<S2_B1, 256, 0, stream>>>(table_all, table2_all, xb, w1f, h1b);

    for (int l = 0; l < 4; l++) {
        const ushort2* table2 = table2_all + (size_t)l * TBL * 64;
        float* sum1 = stats + (size_t)l * 512;
        float* sq1  = sum1 + 128;
        float* sum2 = sum1 + 256;
        float* sq2  = sum1 + 384;
        edge_xagg_kernel<<<NEB + NT * HH / 256, 256, 0, stream>>>(
            cntA, pay_pad, ovf_cnt, ovf, table2, h1b, aggb, xb, xaggb);
        gin_gemm1_kernel<<<NT / 64, 256, 0, stream>>>(
            gcnt, gpay_pad, ovf_cnt, govf, xaggb, bond_emb + (size_t)l * 10 * HH, gin_eps + l,
            gw1f + (size_t)l * HH * HH, gin_b1 + (size_t)l * HH, hgA, sum1, sq1);
        gemm_bn_stats_kernel<<<NT / 64, 256, 0, stream>>>(
            hgA, sum1, sq1, gin_bn_g + (size_t)l * HH, gin_bn_b + (size_t)l * HH,
            gw2f + (size_t)l * HH * HH, gin_b2 + (size_t)l * HH, hgB, sum2, sq2);
        fused_lin_kernel<<<NN / 64, 256, 0, stream>>>(
            aggb, w2f + (size_t)l * FF * HH, cf_lin2_b + (size_t)l * HH,
            wlf + (size_t)l * HH * HH, lin_b + (size_t)l * HH,
            hgB, sum2, sq2, bn_g + (size_t)l * HH, bn_b + (size_t)l * HH,
            cnb, (l < 3) ? (w1f + (size_t)(l + 1) * HH * FF) : nullptr,
            xb, h1b);
    }

    out_layer_kernel<<<MM, 128, 0, stream>>>(xb, out_w1, out_b1, out_w2, out_b2, out);
}

// Round 8
// 583.044 us; speedup vs baseline: 1.0964x; 1.0104x over previous
//
#include <hip/hip_runtime.h>
#include <hip/hip_bf16.h>

#define EC 1048576   // conformer edges
#define NN 65536     // conformer nodes
#define NT 8192      // topo nodes
#define MM 256
#define HH 128
#define FF 64
#define GG 50
#define EG 32768     // graph edges

#define TBL 2048            // Wf table entries per layer (512KB/layer -> L2-resident)
#define TBL_SHIFT 11
#define TRANGE 14.0f

#define CAP 32              // padded-CSR slots per conformer node (Poisson(16))
#define OVF_CAP 8192        // conformer overflow list capacity
#define GCAP 32             // padded-CSR slots per topo node (Poisson(4))
#define GOVF_CAP 1024       // graph overflow list capacity
#define NEB (NN * 64 / 256)     // edge-agg blocks in merged dispatch

// sentinel pay: table index 2047 (never produced by real edges: i0<=2046), fr=0, row=0
// table2[2047] is forced to {0,0} -> contribution exactly 0 without any masking
#define SENT 0xFFE00000

constexpr float STEP = 10.0f / 49.0f;
constexpr float GC = -0.5f / (STEP * STEP);

typedef __attribute__((ext_vector_type(8))) short bf16x8;
typedef __attribute__((ext_vector_type(4))) float f32x4;

__device__ __forceinline__ ushort f2b(float v) {
    __hip_bfloat16 h = __float2bfloat16(v);
    return *(ushort*)&h;
}
__device__ __forceinline__ float b2f(ushort u) {
    return __uint_as_float(((unsigned)u) << 16);
}

// ---------------- weight prep helper ----------------
__device__ __forceinline__ void prep_one(
    const float* __restrict__ W, ushort* __restrict__ Wf, int K, int N, int idx)
{
    int sz = K * N;
    int l = idx / sz;
    int t = idx - l * sz;
    int j = t & 7;
    int lane = (t >> 3) & 63;
    int rest = t >> 9;
    int KTl = K >> 5;
    int kt = rest % KTl;
    int nt = rest / KTl;
    int k = kt * 32 + (lane >> 4) * 8 + j;
    int n = nt * 16 + (lane & 15);
    Wf[idx] = f2b(W[(size_t)l * sz + (size_t)k * N + n]);
}

// ---------------- mega setup: conf scatter + graph scatter + embed + Wf-table + prep --------
// Conformer scatter: 1 edge/thread (measured-best; far-atomic rate is the floor).
// Graph scatter: padded-CSR via same slot trick.
// pay_pad sentinel-filled + cntA/gcnt/ovf_cnt zeroed BEFORE this kernel.
#define SETUP_B0 (EC / 256)
#define SETUP_B1 (SETUP_B0 + EG / 256)
#define SETUP_B2 (SETUP_B1 + NN * HH / 8 / 256)
#define SETUP_B3 (SETUP_B2 + 4 * TBL / 4)
#define SETUP_B4 (SETUP_B3 + 1024)
__global__ __launch_bounds__(256) void setup_kernel(
    const int* __restrict__ eic, const int* __restrict__ cnb,
    const int* __restrict__ eig, const int* __restrict__ eattr,
    const float* __restrict__ pos,
    const float* __restrict__ emb, const int* __restrict__ xtopo,
    ushort* __restrict__ xb,
    int* __restrict__ cntA, int* __restrict__ pay_pad,
    int* __restrict__ ovf_cnt, int2* __restrict__ ovf,
    int* __restrict__ gcnt, int2* __restrict__ gpay_pad, int4* __restrict__ govf,
    const float* __restrict__ mw1, const float* __restrict__ mb1,
    const float* __restrict__ mw2, const float* __restrict__ mb2,
    float* __restrict__ table_all,
    const float* __restrict__ cf_lin1_w, const float* __restrict__ cf_lin2_w,
    const float* __restrict__ lin_w, const float* __restrict__ gin_w1,
    const float* __restrict__ gin_w2,
    ushort* __restrict__ w1f, ushort* __restrict__ w2f, ushort* __restrict__ wlf,
    ushort* __restrict__ gw1f, ushort* __restrict__ gw2f)
{
    int b = blockIdx.x, tid = threadIdx.x;
    if (b < SETUP_B0) {
        // conformer edge: distance + direct padded-CSR scatter (1 edge/thread)
        int e = b * 256 + tid;
        int r = eic[e], c = eic[EC + e];
        float dx = pos[r*3+0] - pos[c*3+0];
        float dy = pos[r*3+1] - pos[c*3+1];
        float dz = pos[r*3+2] - pos[c*3+2];
        float w = sqrtf(dx*dx + dy*dy + dz*dz + 1e-12f);
        float u = fminf(w * ((TBL - 1) / TRANGE), 2046.96875f);
        int pay = (((int)(u * 32.0f)) << 16) | (r & 0xFFFF);   // 11.5 fixed point | row
        int slot = atomicAdd(&cntA[c], 1);
        if (slot < CAP) {
            pay_pad[c * CAP + slot] = pay;
        } else {
            int o = atomicAdd(&ovf_cnt[0], 1);
            if (o < OVF_CAP) ovf[o] = make_int2(c, pay);   // hard bound
        }
    } else if (b < SETUP_B1) {
        // graph edge: padded-CSR scatter
        int e = (b - SETUP_B0) * 256 + tid;
        int src = eig[e], dst = eig[EG + e];
        int at = eattr[e];
        int slot = atomicAdd(&gcnt[dst], 1);
        if (slot < GCAP) {
            gpay_pad[dst * GCAP + slot] = make_int2(src, at);
        } else {
            int o = atomicAdd(&ovf_cnt[1], 1);
            if (o < GOVF_CAP) govf[o] = make_int4(dst, src, at, 0);   // hard bound
        }
    } else if (b < SETUP_B2) {
        // vectorized embedding broadcast: 8 features per thread
        int idx = (b - SETUP_B1) * 256 + tid;   // 0 .. NN*HH/8
        int n = idx >> 4;
        int f8 = (idx & 15) << 3;
        const float* e = emb + (size_t)xtopo[cnb[n]] * HH + f8;
        float4 v0 = *(const float4*)e;
        float4 v1 = *(const float4*)(e + 4);
        ushort u[8] = {f2b(v0.x), f2b(v0.y), f2b(v0.z), f2b(v0.w),
                       f2b(v1.x), f2b(v1.y), f2b(v1.z), f2b(v1.w)};
        *(bf16x8*)(xb + ((size_t)idx << 3)) = *(const bf16x8*)u;
    } else if (b < SETUP_B3) {
        // Wf table: 4 entries per block, one per wave
        int entry = (b - SETUP_B2) * 4 + (tid >> 6);
        int l = entry >> TBL_SHIFT;
        int p = entry & (TBL - 1);
        int lane = tid & 63;
        int wv = tid >> 6;
        const float* w1 = mw1 + (size_t)l * GG * FF;
        const float* b1 = mb1 + (size_t)l * FF;
        const float* w2 = mw2 + (size_t)l * FF * FF;
        const float* b2 = mb2 + (size_t)l * FF;
        float w = p * (TRANGE / (TBL - 1));
        float t = b1[lane];
        for (int g = 0; g < GG; g++) {
            float d = w - g * STEP;
            float ea = __expf(GC * d * d);
            t = fmaf(ea, w1[g * 64 + lane], t);
        }
        __shared__ float ts[4][64];
        ts[wv][lane] = fmaxf(t, 0.f);
        __syncthreads();
        float wf = b2[lane];
        for (int i = 0; i < 64; i++)
            wf = fmaf(ts[wv][i], w2[i * 64 + lane], wf);
        float cw = 0.5f * (__cosf(w * (3.14159265358979323846f / 10.0f)) + 1.0f);
        table_all[((size_t)l * TBL + p) * 64 + lane] = wf * cw;
    } else {
        int pb = b - SETUP_B3;
        if (pb < 128)       prep_one(cf_lin1_w, w1f, HH, FF, pb * 256 + tid);
        else if (pb < 256)  prep_one(cf_lin2_w, w2f, FF, HH, (pb - 128) * 256 + tid);
        else if (pb < 512)  prep_one(lin_w, wlf, HH, HH, (pb - 256) * 256 + tid);
        else if (pb < 768)  prep_one(gin_w1, gw1f, HH, HH, (pb - 512) * 256 + tid);
        else                prep_one(gin_w2, gw2f, HH, HH, (pb - 768) * 256 + tid);
    }
}

// ---------------- stage2: pack table (bf16 pair) + initial h1b GEMM, one dispatch ----------------
#define S2_B0 (4 * TBL * 64 / 256)      // 2048 pack blocks
#define S2_B1 (S2_B0 + NN / 64)         // + 1024 gemm blocks
__global__ __launch_bounds__(256) void stage2_kernel(
    const float* __restrict__ table_all, ushort2* __restrict__ table2_all,
    const ushort* __restrict__ A, const ushort* __restrict__ Bf,
    ushort* __restrict__ Cb)
{
    int b = blockIdx.x, tid = threadIdx.x;
    if (b < S2_B0) {
        int idx = b * 256 + tid;   // 4*TBL*64
        int f = idx & 63;
        int rest = idx >> 6;
        int i = rest & (TBL - 1);
        int l = rest >> TBL_SHIFT;
        if (i == TBL - 1) {
            table2_all[idx] = make_ushort2(0, 0);   // sentinel target {0,0}
            return;
        }
        const float* T = table_all + ((size_t)l * TBL) * 64;
        float t0 = T[(size_t)i * 64 + f];
        float t1 = T[(size_t)(i + 1) * 64 + f];
        // dt prescaled by 1/32 (exact pow2 shift in bf16): wf = fmaf(dts, (float)frac5, t0)
        table2_all[idx] = make_ushort2(f2b(t0), f2b((t1 - t0) * 0.03125f));
    } else {
        // initial h1b = xb @ cf_lin1_w[0], N=64 K=128
        int wave = tid >> 6, lane = tid & 63;
        int m0 = ((b - S2_B0) * 4 + wave) * 16;
        int arow = m0 + (lane & 15);
        int ak = (lane >> 4) * 8;
        bf16x8 a[4];
        const ushort* Ap = A + (size_t)arow * 128 + ak;
        #pragma unroll
        for (int kt = 0; kt < 4; kt++)
            a[kt] = *(const bf16x8*)(Ap + kt * 32);
        f32x4 acc[4];
        #pragma unroll
        for (int i = 0; i < 4; i++) acc[i] = (f32x4){0.f, 0.f, 0.f, 0.f};
        const ushort* Bp = Bf + (size_t)lane * 8;
        #pragma unroll
        for (int nt = 0; nt < 4; nt++)
            #pragma unroll
            for (int kt = 0; kt < 4; kt++) {
                bf16x8 bb = *(const bf16x8*)(Bp + ((size_t)(nt * 4 + kt)) * 512);
                acc[nt] = __builtin_amdgcn_mfma_f32_16x16x32_bf16(a[kt], bb, acc[nt], 0, 0, 0);
            }
        int col0 = lane & 15;
        int rbase = m0 + (lane >> 4) * 4;
        #pragma unroll
        for (int nt = 0; nt < 4; nt++) {
            int col = nt * 16 + col0;
            #pragma unroll
            for (int r = 0; r < 4; r++)
                Cb[(size_t)(rbase + r) * 64 + col] = f2b(acc[nt][r]);
        }
    }
}

// 8-wide edge batch, NO masking (sentinel pays -> exact 0 contribution).
// pp is wave-uniform; pays forced to SGPR via readfirstlane so all the
// unpack/address math runs on the SALU pipe; gathers are saddr+voffset32.
#define EDGE8(BASE) { \
    int pq[8]; \
    { int4 q0 = *(const int4*)(pp + BASE); \
      int4 q1 = *(const int4*)(pp + BASE + 4); \
      pq[0]=__builtin_amdgcn_readfirstlane(q0.x); \
      pq[1]=__builtin_amdgcn_readfirstlane(q0.y); \
      pq[2]=__builtin_amdgcn_readfirstlane(q0.z); \
      pq[3]=__builtin_amdgcn_readfirstlane(q0.w); \
      pq[4]=__builtin_amdgcn_readfirstlane(q1.x); \
      pq[5]=__builtin_amdgcn_readfirstlane(q1.y); \
      pq[6]=__builtin_amdgcn_readfirstlane(q1.z); \
      pq[7]=__builtin_amdgcn_readfirstlane(q1.w); } \
    float h[8]; \
    _Pragma("unroll") \
    for (int q = 0; q < 8; q++) \
        h[q] = b2f(*(const ushort*)(h1c + ((((unsigned)(pq[q] & 0xFFFF)) << 7) + lane2))); \
    unsigned tt[8]; \
    _Pragma("unroll") \
    for (int q = 0; q < 8; q++) \
        tt[q] = *(const unsigned*)(tbc + (((((unsigned)pq[q]) >> 21) << 8) + lane4)); \
    _Pragma("unroll") \
    for (int q = 0; q < 8; q++) { \
        float fr = (float)((unsigned)((pq[q] >> 16) & 31)); \
        float t0 = __uint_as_float(tt[q] << 16); \
        float dts = __uint_as_float(tt[q] & 0xFFFF0000u); \
        float wf = fmaf(dts, fr, t0); \
        if (q & 1) acc1 = fmaf(h[q], wf, acc1); else acc0 = fmaf(h[q], wf, acc0); \
    } }

// 4-wide tail batch (finer granularity halves sentinel waste for slots 16..32)
#define EDGE4(BASE) { \
    int pq[4]; \
    { int4 q0 = *(const int4*)(pp + BASE); \
      pq[0]=__builtin_amdgcn_readfirstlane(q0.x); \
      pq[1]=__builtin_amdgcn_readfirstlane(q0.y); \
      pq[2]=__builtin_amdgcn_readfirstlane(q0.z); \
      pq[3]=__builtin_amdgcn_readfirstlane(q0.w); } \
    float h[4]; \
    _Pragma("unroll") \
    for (int q = 0; q < 4; q++) \
        h[q] = b2f(*(const ushort*)(h1c + ((((unsigned)(pq[q] & 0xFFFF)) << 7) + lane2))); \
    unsigned tt[4]; \
    _Pragma("unroll") \
    for (int q = 0; q < 4; q++) \
        tt[q] = *(const unsigned*)(tbc + (((((unsigned)pq[q]) >> 21) << 8) + lane4)); \
    _Pragma("unroll") \
    for (int q = 0; q < 4; q++) { \
        float fr = (float)((unsigned)((pq[q] >> 16) & 31)); \
        float t0 = __uint_as_float(tt[q] << 16); \
        float dts = __uint_as_float(tt[q] & 0xFFFF0000u); \
        float wf = fmaf(dts, fr, t0); \
        if (q & 1) acc1 = fmaf(h[q], wf, acc1); else acc0 = fmaf(h[q], wf, acc0); \
    } }

// ---------------- merged: padded-CSR edge aggregation + closed-form xagg max ----------------
__global__ __launch_bounds__(256) void edge_xagg_kernel(
    const int* __restrict__ cntA, const int* __restrict__ pay_pad,
    const int* __restrict__ ovf_cnt, const int2* __restrict__ ovf,
    const ushort2* __restrict__ table2, const ushort* __restrict__ h1b,
    ushort* __restrict__ aggb,
    const ushort* __restrict__ xb, ushort* __restrict__ xaggb)
{
    int tid = threadIdx.x;
    if (blockIdx.x < NEB) {
        int lane = tid & 63;
        int node = __builtin_amdgcn_readfirstlane((blockIdx.x * 256 + tid) >> 6);
        unsigned lane2 = (unsigned)lane * 2;
        unsigned lane4 = (unsigned)lane * 4;
        const char* h1c = (const char*)h1b;
        const char* tbc = (const char*)table2;
        int deg = cntA[node];
        int n1 = min(deg, CAP);
        const int* pp = pay_pad + (size_t)node * CAP;
        float acc0 = 0.f, acc1 = 0.f;
        EDGE8(0);
        if (n1 > 8) {
            EDGE8(8);
            if (n1 > 16) {
                EDGE4(16);
                if (n1 > 20) {
                    EDGE4(20);
                    if (n1 > 24) {
                        EDGE4(24);
                        if (n1 > 28) EDGE4(28);
                    }
                }
            }
        }
        float acc = acc0 + acc1;
        if (deg > CAP) {   // rare overflow path (Poisson(16) tail): scan tiny list
            int no = min(ovf_cnt[0], OVF_CAP);   // hard bound
            for (int j = 0; j < no; j++) {
                int2 o = ovf[j];
                if (o.x == node) {
                    unsigned uf = (unsigned)o.y >> 16;
                    int i0 = uf >> 5;
                    float fr = (float)(uf & 31);
                    ushort2 ttv = table2[(size_t)i0 * 64 + lane];
                    acc = fmaf(b2f(h1b[(size_t)(o.y & 0xFFFF) * 64 + lane]),
                               fmaf(b2f(ttv.y), fr, b2f(ttv.x)), acc);
                }
            }
        }
        aggb[(size_t)node * 64 + lane] = f2b(acc);
    } else {
        int idx = (blockIdx.x - NEB) * 256 + tid;   // NT*HH
        int tn = idx >> 7, f = idx & 127;
        int m = tn >> 5, a = tn & 31;
        const ushort* base = xb + ((size_t)((m << 8) + a)) * HH + f;
        float mx = -3.4e38f;
        #pragma unroll
        for (int k = 0; k < 8; k++)
            mx = fmaxf(mx, b2f(base[(size_t)(k << 5) * HH]));
        xaggb[idx] = f2b(mx);
    }
}

#define TSTR 136

// ---------------- GIN GEMM1, 256 blocks x 128 threads (fills all CUs) ----------------
// 32 topo rows per block; fused magg/hg0 tile build + stats (bf16 hgA out)
__global__ __launch_bounds__(128) void gin_gemm1_kernel(
    const int* __restrict__ gcnt, const int2* __restrict__ gpay_pad,
    const int* __restrict__ ovf_cnt, const int4* __restrict__ govf,
    const ushort* __restrict__ xaggb, const float* __restrict__ bemb,
    const float* __restrict__ eps, const ushort* __restrict__ Bf,
    const float* __restrict__ bias, ushort* __restrict__ Cb,
    float* __restrict__ gsum, float* __restrict__ gsq)
{
    __shared__ ushort hg0s[32 * TSTR];
    __shared__ float ssum[128], ssq[128];
    int tid = threadIdx.x;
    ssum[tid] = 0.f; ssq[tid] = 0.f;
    {
        int row = tid >> 2;              // 0..31
        int fc = (tid & 3) * 32;
        int tn = blockIdx.x * 32 + row;
        float e1 = 1.0f + eps[0];
        float acc[32];
        const ushort* xo = xaggb + (size_t)tn * HH + fc;
        #pragma unroll
        for (int c = 0; c < 4; c++) {
            bf16x8 x = *(const bf16x8*)(xo + c * 8);
            #pragma unroll
            for (int j = 0; j < 8; j++)
                acc[c * 8 + j] = e1 * b2f((ushort)x[j]);
        }
        int deg = gcnt[tn];
        int gn = min(deg, GCAP);
        const int2* gp = gpay_pad + (size_t)tn * GCAP;
        for (int p = 0; p < gn; p++) {
            int2 g = gp[p];
            const ushort* xs = xaggb + (size_t)g.x * HH + fc;
            const float* bs = bemb + (size_t)g.y * HH + fc;
            #pragma unroll
            for (int c = 0; c < 4; c++) {
                bf16x8 x = *(const bf16x8*)(xs + c * 8);
                float4 b0 = *(const float4*)(bs + c * 8);
                float4 b1 = *(const float4*)(bs + c * 8 + 4);
                float bb[8] = {b0.x, b0.y, b0.z, b0.w, b1.x, b1.y, b1.z, b1.w};
                #pragma unroll
                for (int j = 0; j < 8; j++)
                    acc[c * 8 + j] += fmaxf(b2f((ushort)x[j]) + bb[j], 0.f);
            }
        }
        if (deg > GCAP) {   // rare overflow path
            int no = min(ovf_cnt[1], GOVF_CAP);
            for (int j2 = 0; j2 < no; j2++) {
                int4 o = govf[j2];
                if (o.x == tn) {
                    const ushort* xs = xaggb + (size_t)o.y * HH + fc;
                    const float* bs = bemb + (size_t)o.z * HH + fc;
                    #pragma unroll
                    for (int c = 0; c < 4; c++) {
                        bf16x8 x = *(const bf16x8*)(xs + c * 8);
                        float4 b0 = *(const float4*)(bs + c * 8);
                        float4 b1 = *(const float4*)(bs + c * 8 + 4);
                        float bb[8] = {b0.x, b0.y, b0.z, b0.w, b1.x, b1.y, b1.z, b1.w};
                        #pragma unroll
                        for (int j = 0; j < 8; j++)
                            acc[c * 8 + j] += fmaxf(b2f((ushort)x[j]) + bb[j], 0.f);
                    }
                }
            }
        }
        ushort* dst = hg0s + row * TSTR + fc;
        #pragma unroll
        for (int j = 0; j < 32; j++) dst[j] = f2b(acc[j]);
    }
    __syncthreads();
    int wave = tid >> 6, lane = tid & 63;   // 2 waves
    int lm = lane & 15, lq = lane >> 4;
    int ak = lq * 8;
    bf16x8 a[4];
    #pragma unroll
    for (int kt = 0; kt < 4; kt++)
        a[kt] = *(const bf16x8*)&hg0s[(wave * 16 + lm) * TSTR + ak + kt * 32];
    f32x4 acc[8];
    #pragma unroll
    for (int i = 0; i < 8; i++) acc[i] = (f32x4){0.f, 0.f, 0.f, 0.f};
    const ushort* Bp = Bf + (size_t)lane * 8;
    #pragma unroll
    for (int nt = 0; nt < 8; nt++)
        #pragma unroll
        for (int kt = 0; kt < 4; kt++) {
            bf16x8 b = *(const bf16x8*)(Bp + ((size_t)(nt * 4 + kt)) * 512);
            acc[nt] = __builtin_amdgcn_mfma_f32_16x16x32_bf16(a[kt], b, acc[nt], 0, 0, 0);
        }
    int rbase = blockIdx.x * 32 + wave * 16 + lq * 4;
    #pragma unroll
    for (int nt = 0; nt < 8; nt++) {
        int col = nt * 16 + lm;
        float bs = bias[col];
        float ps = 0.f, pq = 0.f;
        #pragma unroll
        for (int r = 0; r < 4; r++) {
            float v = acc[nt][r] + bs;
            Cb[(size_t)(rbase + r) * 128 + col] = f2b(v);
            ps += v; pq += v * v;
        }
        atomicAdd(&ssum[col], ps);
        atomicAdd(&ssq[col], pq);
    }
    __syncthreads();
    atomicAdd(&gsum[tid], ssum[tid]);
    atomicAdd(&gsq[tid], ssq[tid]);
}

// ---------------- GIN gemm 2, 256 blocks x 128 threads ----------------
__global__ __launch_bounds__(128) void gemm_bn_stats_kernel(
    const ushort* __restrict__ Araw, const float* __restrict__ sum1,
    const float* __restrict__ sq1, const float* __restrict__ g1,
    const float* __restrict__ bb1, const ushort* __restrict__ Bf,
    const float* __restrict__ bias, ushort* __restrict__ Cb,
    float* __restrict__ gsum, float* __restrict__ gsq)
{
    __shared__ float ssum[128], ssq[128];
    int tid = threadIdx.x;
    ssum[tid] = 0.f; ssq[tid] = 0.f;
    __syncthreads();
    int wave = tid >> 6, lane = tid & 63;   // 2 waves
    int m0 = (blockIdx.x * 2 + wave) * 16;
    int arow = m0 + (lane & 15);
    int ak = (lane >> 4) * 8;
    const float INV_NT = 1.0f / NT;
    bf16x8 a[4];
    const ushort* Ap = Araw + (size_t)arow * 128 + ak;
    #pragma unroll
    for (int kt = 0; kt < 4; kt++) {
        bf16x8 raw = *(const bf16x8*)(Ap + kt * 32);
        ushort ub[8];
        #pragma unroll
        for (int j = 0; j < 8; j++) {
            int k = ak + kt * 32 + j;
            float mu = sum1[k] * INV_NT;
            float var = sq1[k] * INV_NT - mu * mu;
            float inv = rsqrtf(var + 1e-5f);
            float w = fmaxf((b2f((ushort)raw[j]) - mu) * inv * g1[k] + bb1[k], 0.f);
            ub[j] = f2b(w);
        }
        a[kt] = *(bf16x8*)ub;
    }
    f32x4 acc[8];
    #pragma unroll
    for (int i = 0; i < 8; i++) acc[i] = (f32x4){0.f, 0.f, 0.f, 0.f};
    const ushort* Bp = Bf + (size_t)lane * 8;
    #pragma unroll
    for (int nt = 0; nt < 8; nt++)
        #pragma unroll
        for (int kt = 0; kt < 4; kt++) {
            bf16x8 b = *(const bf16x8*)(Bp + ((size_t)(nt * 4 + kt)) * 512);
            acc[nt] = __builtin_amdgcn_mfma_f32_16x16x32_bf16(a[kt], b, acc[nt], 0, 0, 0);
        }
    int col0 = lane & 15;
    int rbase = m0 + (lane >> 4) * 4;
    #pragma unroll
    for (int nt = 0; nt < 8; nt++) {
        int col = nt * 16 + col0;
        float bs = bias[col];
        float ps = 0.f, pq = 0.f;
        #pragma unroll
        for (int r = 0; r < 4; r++) {
            float v = acc[nt][r] + bs;
            Cb[(size_t)(rbase + r) * 128 + col] = f2b(v);
            ps += v; pq += v * v;
        }
        atomicAdd(&ssum[col], ps);
        atomicAdd(&ssq[col], pq);
    }
    __syncthreads();
    atomicAdd(&gsum[tid], ssum[tid]);
    atomicAdd(&gsq[tid], ssq[tid]);
}

// ---------------- fused CFConv tail: 3 chained GEMMs, coalesced epilogues ----------------
__global__ __launch_bounds__(256) void fused_lin_kernel(
    const ushort* __restrict__ aggb, const ushort* __restrict__ w2,
    const float* __restrict__ b2, const ushort* __restrict__ w3,
    const float* __restrict__ b3, const ushort* __restrict__ hgBb,
    const float* __restrict__ sum2, const float* __restrict__ sq2,
    const float* __restrict__ g2, const float* __restrict__ bb2,
    const int* __restrict__ cnb, const ushort* __restrict__ w1n,
    ushort* __restrict__ xb, ushort* __restrict__ h1b)
{
    __shared__ ushort t1s[4][16 * TSTR];
    __shared__ ushort t2s[4][16 * TSTR];
    int tid = threadIdx.x;
    int wave = tid >> 6, lane = tid & 63;
    int m0 = (blockIdx.x * 4 + wave) * 16;
    int lm = lane & 15;
    int lq = lane >> 4;
    ushort* T1 = t1s[wave];
    ushort* T2 = t2s[wave];
    const float INV_NT = 1.0f / NT;

    const ushort* Ap = aggb + (size_t)(m0 + lm) * 64 + lq * 8;
    bf16x8 a1[2];
    a1[0] = *(const bf16x8*)(Ap);
    a1[1] = *(const bf16x8*)(Ap + 32);
    f32x4 acc[8];
    #pragma unroll
    for (int i = 0; i < 8; i++) acc[i] = (f32x4){0.f, 0.f, 0.f, 0.f};
    {
        const ushort* Bp = w2 + (size_t)lane * 8;
        #pragma unroll
        for (int nt = 0; nt < 8; nt++)
            #pragma unroll
            for (int kt = 0; kt < 2; kt++) {
                bf16x8 b = *(const bf16x8*)(Bp + ((size_t)(nt * 2 + kt)) * 512);
                acc[nt] = __builtin_amdgcn_mfma_f32_16x16x32_bf16(a1[kt], b, acc[nt], 0, 0, 0);
            }
    }
    #pragma unroll
    for (int nt = 0; nt < 8; nt++) {
        int col = nt * 16 + lm;
        float bs = b2[col];
        #pragma unroll
        for (int r = 0; r < 4; r++) {
            float v = fmaxf(acc[nt][r] + bs, 0.f);
            T1[(lq * 4 + r) * TSTR + col] = f2b(v);
        }
    }
    __syncthreads();

    bf16x8 a2[4];
    #pragma unroll
    for (int kt = 0; kt < 4; kt++)
        a2[kt] = *(const bf16x8*)&T1[lm * TSTR + kt * 32 + lq * 8];
    __syncthreads();
    #pragma unroll
    for (int i = 0; i < 4; i++) {
        int idx = i * 64 + lane;
        int row = idx >> 4, ch = idx & 15;
        bf16x8 v = *(const bf16x8*)(xb + (size_t)(m0 + row) * HH + ch * 8);
        *(bf16x8*)&T1[row * TSTR + ch * 8] = v;
    }
    #pragma unroll
    for (int i = 0; i < 8; i++) acc[i] = (f32x4){0.f, 0.f, 0.f, 0.f};
    {
        const ushort* Bp = w3 + (size_t)lane * 8;
        #pragma unroll
        for (int nt = 0; nt < 8; nt++)
            #pragma unroll
            for (int kt = 0; kt < 4; kt++) {
                bf16x8 b = *(const bf16x8*)(Bp + ((size_t)(nt * 4 + kt)) * 512);
                acc[nt] = __builtin_amdgcn_mfma_f32_16x16x32_bf16(a2[kt], b, acc[nt], 0, 0, 0);
            }
    }
    int rbase = m0 + lq * 4;
    int cn[4];
    #pragma unroll
    for (int r = 0; r < 4; r++) cn[r] = cnb[rbase + r];
    #pragma unroll
    for (int nt = 0; nt < 8; nt++) {
        int col = nt * 16 + lm;
        float bs = b3[col];
        float mu2 = sum2[col] * INV_NT;
        float var2 = sq2[col] * INV_NT - mu2 * mu2;
        float sc2 = rsqrtf(var2 + 1e-5f) * g2[col];
        float sh2 = bb2[col] - mu2 * sc2;
        #pragma unroll
        for (int r = 0; r < 4; r++) {
            float v = acc[nt][r] + bs;
            v += b2f(T1[(lq * 4 + r) * TSTR + col]);
            v = fmaf(b2f(hgBb[(size_t)cn[r] * HH + col]), sc2, v + sh2);
            v = fmaxf(v, 0.f);
            T2[(lq * 4 + r) * TSTR + col] = f2b(v);
        }
    }
    __syncthreads();
    #pragma unroll
    for (int i = 0; i < 4; i++) {
        int idx = i * 64 + lane;
        int row = idx >> 4, ch = idx & 15;
        bf16x8 v = *(const bf16x8*)&T2[row * TSTR + ch * 8];
        *(bf16x8*)(xb + (size_t)(m0 + row) * HH + ch * 8) = v;
    }
    if (!w1n) return;
    __syncthreads();

    bf16x8 a3[4];
    #pragma unroll
    for (int kt = 0; kt < 4; kt++)
        a3[kt] = *(const bf16x8*)&T2[lm * TSTR + kt * 32 + lq * 8];
    f32x4 acc3[4];
    #pragma unroll
    for (int i = 0; i < 4; i++) acc3[i] = (f32x4){0.f, 0.f, 0.f, 0.f};
    {
        const ushort* Bp = w1n + (size_t)lane * 8;
        #pragma unroll
        for (int nt = 0; nt < 4; nt++)
            #pragma unroll
            for (int kt = 0; kt < 4; kt++) {
                bf16x8 b = *(const bf16x8*)(Bp + ((size_t)(nt * 4 + kt)) * 512);
                acc3[nt] = __builtin_amdgcn_mfma_f32_16x16x32_bf16(a3[kt], b, acc3[nt], 0, 0, 0);
            }
    }
    #pragma unroll
    for (int nt = 0; nt < 4; nt++) {
        int col = nt * 16 + lm;
        #pragma unroll
        for (int r = 0; r < 4; r++)
            T1[(lq * 4 + r) * TSTR + col] = f2b(acc3[nt][r]);
    }
    __syncthreads();
    #pragma unroll
    for (int i = 0; i < 2; i++) {
        int idx = i * 64 + lane;
        int row = idx >> 3, ch = idx & 7;
        bf16x8 v = *(const bf16x8*)&T1[row * TSTR + ch * 8];
        *(bf16x8*)(h1b + (size_t)(m0 + row) * FF + ch * 8) = v;
    }
}

// ---------------- output head with fused two-level max pool ----------------
__global__ __launch_bounds__(128) void out_layer_kernel(
    const ushort* __restrict__ xb, const float* __restrict__ w1,
    const float* __restrict__ b1, const float* __restrict__ w2,
    const float* __restrict__ b2, float* __restrict__ out)
{
    int m = blockIdx.x, f = threadIdx.x;
    const ushort* base = xb + (size_t)m * 256 * HH + f;
    float mx = -3.4e38f;
    for (int r = 0; r < 256; r++)
        mx = fmaxf(mx, b2f(base[(size_t)r * HH]));
    __shared__ float xs[128];
    xs[f] = mx;
    __syncthreads();
    float acc = b1[f];
    for (int k = 0; k < 128; k++) acc = fmaf(xs[k], w1[k * HH + f], acc);
    acc = fmaxf(acc, 0.f) * w2[f];
    __shared__ float red[128];
    red[f] = acc;
    __syncthreads();
    for (int off = 64; off > 0; off >>= 1) {
        if (f < off) red[f] += red[f + off];
        __syncthreads();
    }
    if (f == 0) out[m] = red[0] + b2[0];
}

extern "C" void kernel_launch(void* const* d_in, const int* in_sizes, int n_in,
                              void* d_out, int out_size, void* d_ws, size_t ws_size,
                              hipStream_t stream)
{
    const int*   x_topo    = (const int*)d_in[0];
    const float* pos       = (const float*)d_in[1];
    const int*   eic       = (const int*)d_in[2];
    const int*   eig       = (const int*)d_in[3];
    const int*   eattr     = (const int*)d_in[4];
    const int*   cnb       = (const int*)d_in[5];
    const float* atom_emb  = (const float*)d_in[8];
    const float* cf_lin1_w = (const float*)d_in[9];
    const float* cf_mlp_w1 = (const float*)d_in[10];
    const float* cf_mlp_b1 = (const float*)d_in[11];
    const float* cf_mlp_w2 = (const float*)d_in[12];
    const float* cf_mlp_b2 = (const float*)d_in[13];
    const float* cf_lin2_w = (const float*)d_in[14];
    const float* cf_lin2_b = (const float*)d_in[15];
    const float* lin_w     = (const float*)d_in[16];
    const float* lin_b     = (const float*)d_in[17];
    const float* bond_emb  = (const float*)d_in[18];
    const float* gin_w1    = (const float*)d_in[19];
    const float* gin_b1    = (const float*)d_in[20];
    const float* gin_w2    = (const float*)d_in[21];
    const float* gin_b2    = (const float*)d_in[22];
    const float* gin_bn_g  = (const float*)d_in[23];
    const float* gin_bn_b  = (const float*)d_in[24];
    const float* bn_g      = (const float*)d_in[25];
    const float* bn_b      = (const float*)d_in[26];
    const float* gin_eps   = (const float*)d_in[27];
    const float* out_w1    = (const float*)d_in[28];
    const float* out_b1    = (const float*)d_in[29];
    const float* out_w2    = (const float*)d_in[30];
    const float* out_b2    = (const float*)d_in[31];
    float* out = (float*)d_out;

    char* wsb = (char*)d_ws;
    size_t off = 0;
    auto alloc = [&](size_t nbytes) -> void* {
        void* p = (void*)(wsb + off);
        off += (nbytes + 255) & ~(size_t)255;
        return p;
    };
    ushort* xb      = (ushort*)alloc((size_t)NN * HH * 2);
    ushort* h1b     = (ushort*)alloc((size_t)NN * FF * 2);
    ushort* aggb    = (ushort*)alloc((size_t)NN * FF * 2);
    ushort* xaggb   = (ushort*)alloc((size_t)NT * HH * 2);
    ushort* hgA     = (ushort*)alloc((size_t)NT * HH * 2);
    ushort* hgB     = (ushort*)alloc((size_t)NT * HH * 2);
    float*  table_all  = (float*)alloc((size_t)4 * TBL * 64 * 4);
    ushort2* table2_all = (ushort2*)alloc((size_t)4 * TBL * 64 * 4);
    // stats + cntA + gcnt + ovf_cnt adjacent -> single memset (ovf_cnt[0]=conf, [1]=graph)
    float*  stats   = (float*)alloc((size_t)4 * 4 * 128 * 4);     // 8 KB
    int*    cntA    = (int*)alloc((size_t)NN * 4);                // 256 KB
    int*    gcnt    = (int*)alloc((size_t)NT * 4);                // 32 KB
    int*    ovf_cnt = (int*)alloc(256);                           // 256 B
    int*    pay_pad = (int*)alloc((size_t)NN * CAP * 4);          // 8 MB padded CSR
    int2*   ovf     = (int2*)alloc((size_t)OVF_CAP * 8);
    int2*   gpay_pad = (int2*)alloc((size_t)NT * GCAP * 8);       // 2 MB padded graph CSR
    int4*   govf    = (int4*)alloc((size_t)GOVF_CAP * 16);
    ushort* w1f     = (ushort*)alloc((size_t)4 * HH * FF * 2);
    ushort* w2f     = (ushort*)alloc((size_t)4 * FF * HH * 2);
    ushort* wlf     = (ushort*)alloc((size_t)4 * HH * HH * 2);
    ushort* gw1f    = (ushort*)alloc((size_t)4 * HH * HH * 2);
    ushort* gw2f    = (ushort*)alloc((size_t)4 * HH * HH * 2);

    // --- single memset covering stats + cntA + gcnt + ovf_cnt (adjacent, 256B-aligned) ---
    hipMemsetAsync(stats, 0,
        ((size_t)4 * 4 * 128 * 4 + 255 & ~(size_t)255) +
        ((size_t)NN * 4 + 255 & ~(size_t)255) +
        ((size_t)NT * 4 + 255 & ~(size_t)255) + 256, stream);
    // --- sentinel fill of padded conformer CSR ---
    hipMemsetD32Async((hipDeviceptr_t)pay_pad, SENT, (size_t)NN * CAP, stream);

    // --- mega setup: conf scatter + graph scatter + embed + Wf-table + weight prep ---
    setup_kernel<<<SETUP_B4, 256, 0, stream>>>(
        eic, cnb, eig, eattr, pos, atom_emb, x_topo, xb,
        cntA, pay_pad, ovf_cnt, ovf, gcnt, gpay_pad, govf,
        cf_mlp_w1, cf_mlp_b1, cf_mlp_w2, cf_mlp_b2, table_all,
        cf_lin1_w, cf_lin2_w, lin_w, gin_w1, gin_w2, w1f, w2f, wlf, gw1f, gw2f);
    // --- stage2: pack table + initial h1b GEMM ---
    stage2_kernel<<<S2_B1, 256, 0, stream>>>(table_all, table2_all, xb, w1f, h1b);

    for (int l = 0; l < 4; l++) {
        const ushort2* table2 = table2_all + (size_t)l * TBL * 64;
        float* sum1 = stats + (size_t)l * 512;
        float* sq1  = sum1 + 128;
        float* sum2 = sum1 + 256;
        float* sq2  = sum1 + 384;
        edge_xagg_kernel<<<NEB + NT * HH / 256, 256, 0, stream>>>(
            cntA, pay_pad, ovf_cnt, ovf, table2, h1b, aggb, xb, xaggb);
        gin_gemm1_kernel<<<NT / 32, 128, 0, stream>>>(
            gcnt, gpay_pad, ovf_cnt, govf, xaggb, bond_emb + (size_t)l * 10 * HH, gin_eps + l,
            gw1f + (size_t)l * HH * HH, gin_b1 + (size_t)l * HH, hgA, sum1, sq1);
        gemm_bn_stats_kernel<<<NT / 32, 128, 0, stream>>>(
            hgA, sum1, sq1, gin_bn_g + (size_t)l * HH, gin_bn_b + (size_t)l * HH,
            gw2f + (size_t)l * HH * HH, gin_b2 + (size_t)l * HH, hgB, sum2, sq2);
        fused_lin_kernel<<<NN / 64, 256, 0, stream>>>(
            aggb, w2f + (size_t)l * FF * HH, cf_lin2_b + (size_t)l * HH,
            wlf + (size_t)l * HH * HH, lin_b + (size_t)l * HH,
            hgB, sum2, sq2, bn_g + (size_t)l * HH, bn_b + (size_t)l * HH,
            cnb, (l < 3) ? (w1f + (size_t)(l + 1) * HH * FF) : nullptr,
            xb, h1b);
    }

    out_layer_kernel<<<MM, 128, 0, stream>>>(xb, out_w1, out_b1, out_w2, out_b2, out);
}